// Round 1
// baseline (1752.959 us; speedup 1.0000x reference)
//
#include <hip/hip_runtime.h>
#include <hip/hip_bf16.h>

// Problem constants
#define BATCH 2
#define SLEN  2048
#define DM    1024
#define NH    16
#define NKH   4
#define HD    64
// Q proj width = NH*HD = 1024, K/V proj width = NKH*HD = 256

// ---------------------------------------------------------------------------
// Generic fp32 tiled GEMM: C[M,N] = A[M,K] @ B[K,N]
// BM=BN=64, BK=16, 256 threads, 4x4 microtile per thread.
// All dims here are multiples of the tiles (M=4096, N in {1024,256}, K=1024).
// ---------------------------------------------------------------------------
__global__ __launch_bounds__(256) void gemm_f32(
    const float* __restrict__ A, const float* __restrict__ Bm,
    float* __restrict__ C, int M, int N, int Kd)
{
    const int t  = threadIdx.x;
    const int tx = t & 15;        // micro col group
    const int ty = t >> 4;        // micro row group
    const int n0 = blockIdx.x * 64;
    const int m0 = blockIdx.y * 64;

    __shared__ float As[16][65];  // [k][m], +1 pad (scalar access only)
    __shared__ float Bs[16][64];  // [k][n], rows 16B-aligned for float4 reads

    float acc[4][4];
#pragma unroll
    for (int i = 0; i < 4; ++i)
#pragma unroll
        for (int j = 0; j < 4; ++j) acc[i][j] = 0.f;

    for (int kt = 0; kt < Kd; kt += 16) {
        // Load A tile 64x16 (transpose into As[k][m]); one float4 per thread.
        {
            const int m  = t >> 2;
            const int kc = (t & 3) * 4;
            const float4 av = *(const float4*)(A + (size_t)(m0 + m) * Kd + kt + kc);
            As[kc + 0][m] = av.x; As[kc + 1][m] = av.y;
            As[kc + 2][m] = av.z; As[kc + 3][m] = av.w;
            // Load B tile 16x64; one float4 per thread.
            const int kr = t >> 4;
            const int nc = (t & 15) * 4;
            *(float4*)&Bs[kr][nc] =
                *(const float4*)(Bm + (size_t)(kt + kr) * N + n0 + nc);
        }
        __syncthreads();
#pragma unroll
        for (int kk = 0; kk < 16; ++kk) {
            const float a0 = As[kk][ty * 4 + 0];
            const float a1 = As[kk][ty * 4 + 1];
            const float a2 = As[kk][ty * 4 + 2];
            const float a3 = As[kk][ty * 4 + 3];
            const float4 b = *(const float4*)&Bs[kk][tx * 4];
            acc[0][0] += a0 * b.x; acc[0][1] += a0 * b.y; acc[0][2] += a0 * b.z; acc[0][3] += a0 * b.w;
            acc[1][0] += a1 * b.x; acc[1][1] += a1 * b.y; acc[1][2] += a1 * b.z; acc[1][3] += a1 * b.w;
            acc[2][0] += a2 * b.x; acc[2][1] += a2 * b.y; acc[2][2] += a2 * b.z; acc[2][3] += a2 * b.w;
            acc[3][0] += a3 * b.x; acc[3][1] += a3 * b.y; acc[3][2] += a3 * b.z; acc[3][3] += a3 * b.w;
        }
        __syncthreads();
    }

#pragma unroll
    for (int i = 0; i < 4; ++i) {
        float4 o;
        o.x = acc[i][0]; o.y = acc[i][1]; o.z = acc[i][2]; o.w = acc[i][3];
        *(float4*)(C + (size_t)(m0 + ty * 4 + i) * N + n0 + tx * 4) = o;
    }
}

// ---------------------------------------------------------------------------
// RoPE (in-place). P is [B, S, nh*64]. cos/sin are [S, 64] with identical
// halves (emb = concat(freqs, freqs)), so we index d < 32 only.
// One thread per (b, s, h, d<32) pair.
// ---------------------------------------------------------------------------
__global__ void rope_k(float* __restrict__ P, const float* __restrict__ cosp,
                       const float* __restrict__ sinp, int nh, int total)
{
    const int idx = blockIdx.x * blockDim.x + threadIdx.x;
    if (idx >= total) return;
    const int d  = idx & 31;
    const int h  = (idx >> 5) % nh;
    const int bs = (idx >> 5) / nh;      // b*S + s
    const int s  = bs & (SLEN - 1);
    float* p = P + (size_t)bs * (nh * HD) + h * HD;
    const float cv = cosp[s * HD + d];
    const float sv = sinp[s * HD + d];
    const float x0 = p[d];
    const float x1 = p[d + 32];
    p[d]      = x0 * cv - x1 * sv;
    p[d + 32] = x1 * cv + x0 * sv;
}

// ---------------------------------------------------------------------------
// Flash attention, fp32, causal, GQA (head h uses kv-head h>>2).
// Block = 256 threads (4 waves). Tile: 64 queries x 64 keys.
// Thread (tx = t&63, ty = t>>6): owns output dims d=tx for queries
// q = ty + 4*q8 (q8 = 0..15)  -> acc[16] registers.
// ---------------------------------------------------------------------------
__global__ __launch_bounds__(256) void flash_attn(
    const float* __restrict__ Q, const float* __restrict__ Kg,
    const float* __restrict__ Vg, float* __restrict__ O)
{
    const int qt = blockIdx.x;     // query tile 0..31
    const int h  = blockIdx.y;     // 0..15
    const int b  = blockIdx.z;     // 0..1
    const int kh = h >> 2;
    const int t  = threadIdx.x;
    const int tx = t & 63;
    const int ty = t >> 6;
    const int q0 = qt * 64;

    __shared__ float Qs[64][64];    // [q][d], rows 16B aligned (float4 broadcast reads)
    __shared__ float Ks[64][65];    // [k][d], +1 pad (scalar reads, conflict-free)
    __shared__ float VsT[64][65];   // [d][k], +1 pad (scalar reads, conflict-free)
    __shared__ float Ss[64][64];    // [q][k], rows 16B aligned
    __shared__ float mS[64], lS[64], aS[64];

    // Load Q tile (64 rows x 64 cols): thread covers f4-col (t&15), rows (t>>4)+16i
    {
        const int fc = (t & 15) * 4;
        const int r0 = t >> 4;
#pragma unroll
        for (int i = 0; i < 4; ++i) {
            const int r = r0 + 16 * i;
            const float4 qv = *(const float4*)(Q + ((size_t)(b * SLEN + q0 + r)) * (NH * HD) + h * HD + fc);
            *(float4*)&Qs[r][fc] = qv;
        }
    }
    if (t < 64) { mS[t] = -1e30f; lS[t] = 0.f; }

    float acc[16];
#pragma unroll
    for (int i = 0; i < 16; ++i) acc[i] = 0.f;

    for (int kt = 0; kt <= qt; ++kt) {
        const int k0 = kt * 64;
        __syncthreads();   // protect LDS overwrite (and Q/m/l init on first iter)
        {
            const int fc = (t & 15) * 4;
            const int r0 = t >> 4;
#pragma unroll
            for (int i = 0; i < 4; ++i) {
                const int r = r0 + 16 * i;
                const float4 kv = *(const float4*)(Kg + ((size_t)(b * SLEN + k0 + r)) * (NKH * HD) + kh * HD + fc);
                Ks[r][fc + 0] = kv.x; Ks[r][fc + 1] = kv.y;
                Ks[r][fc + 2] = kv.z; Ks[r][fc + 3] = kv.w;
                const float4 vv = *(const float4*)(Vg + ((size_t)(b * SLEN + k0 + r)) * (NKH * HD) + kh * HD + fc);
                VsT[fc + 0][r] = vv.x; VsT[fc + 1][r] = vv.y;
                VsT[fc + 2][r] = vv.z; VsT[fc + 3][r] = vv.w;
            }
        }
        __syncthreads();

        // ---- score phase: lane tx = key, queries ty + 4*q8 ----
        {
            float krow[64];
#pragma unroll
            for (int d = 0; d < 64; ++d) krow[d] = Ks[tx][d];
#pragma unroll
            for (int q8 = 0; q8 < 16; ++q8) {
                const int q = ty + (q8 << 2);
                float s = 0.f;
#pragma unroll
                for (int d4 = 0; d4 < 16; ++d4) {
                    const float4 qv = *(const float4*)&Qs[q][d4 * 4];
                    s += qv.x * krow[d4 * 4 + 0] + qv.y * krow[d4 * 4 + 1]
                       + qv.z * krow[d4 * 4 + 2] + qv.w * krow[d4 * 4 + 3];
                }
                s *= 0.125f;   // 1/sqrt(64)
                if (k0 + tx > q0 + q) s = -1e30f;  // causal (only bites on diagonal tile)
                Ss[q][tx] = s;
            }
        }
        __syncthreads();

        // ---- online softmax: wave ty owns rows ty*16..ty*16+15, lane tx = key ----
        for (int i = 0; i < 16; ++i) {
            const int q = (ty << 4) + i;
            const float s = Ss[q][tx];
            float mt = s;
#pragma unroll
            for (int off = 32; off; off >>= 1) mt = fmaxf(mt, __shfl_xor(mt, off));
            const float mo = mS[q];
            const float mn = fmaxf(mo, mt);
            const float p  = __expf(s - mn);
            float ps = p;
#pragma unroll
            for (int off = 32; off; off >>= 1) ps += __shfl_xor(ps, off);
            if (tx == 0) {
                const float al = __expf(mo - mn);
                mS[q] = mn;
                lS[q] = lS[q] * al + ps;
                aS[q] = al;
            }
            Ss[q][tx] = p;
        }
        __syncthreads();

        // ---- PV phase: lane tx = output dim, queries ty + 4*q8 ----
        {
            float vrow[64];
#pragma unroll
            for (int k = 0; k < 64; ++k) vrow[k] = VsT[tx][k];
#pragma unroll
            for (int q8 = 0; q8 < 16; ++q8) {
                const int q = ty + (q8 << 2);
                float a = acc[q8] * aS[q];
#pragma unroll
                for (int k4 = 0; k4 < 16; ++k4) {
                    const float4 pv = *(const float4*)&Ss[q][k4 * 4];
                    a += pv.x * vrow[k4 * 4 + 0] + pv.y * vrow[k4 * 4 + 1]
                       + pv.z * vrow[k4 * 4 + 2] + pv.w * vrow[k4 * 4 + 3];
                }
                acc[q8] = a;
            }
        }
    }

    // epilogue: O[b, q0+q, h*64 + tx] = acc / l   (lS final after last softmax+barrier)
#pragma unroll
    for (int q8 = 0; q8 < 16; ++q8) {
        const int q = ty + (q8 << 2);
        O[((size_t)(b * SLEN + q0 + q)) * (NH * HD) + h * HD + tx] = acc[q8] / lS[q];
    }
}

// ---------------------------------------------------------------------------
extern "C" void kernel_launch(void* const* d_in, const int* in_sizes, int n_in,
                              void* d_out, int out_size, void* d_ws, size_t ws_size,
                              hipStream_t stream) {
    const float* x    = (const float*)d_in[0];   // [B,S,DM]
    const float* cosp = (const float*)d_in[1];   // [S,HD]
    const float* sinp = (const float*)d_in[2];   // [S,HD]
    const float* wq   = (const float*)d_in[3];   // [DM, NH*HD]
    const float* wk   = (const float*)d_in[4];   // [DM, NKH*HD]
    const float* wv   = (const float*)d_in[5];   // [DM, NKH*HD]
    const float* wo   = (const float*)d_in[6];   // [NH*HD, DM]
    float* out = (float*)d_out;                  // [B,S,DM] fp32

    // workspace layout (floats): Q | K | V | O_attn   (total 40 MB)
    float* Qw = (float*)d_ws;                    // 4096*1024
    float* Kw = Qw + (size_t)4096 * 1024;        // 4096*256
    float* Vw = Kw + (size_t)4096 * 256;         // 4096*256
    float* Ow = Vw + (size_t)4096 * 256;         // 4096*1024

    const int Mrows = BATCH * SLEN;              // 4096

    // QKV projections
    gemm_f32<<<dim3((NH * HD) / 64, Mrows / 64), 256, 0, stream>>>(x, wq, Qw, Mrows, NH * HD, DM);
    gemm_f32<<<dim3((NKH * HD) / 64, Mrows / 64), 256, 0, stream>>>(x, wk, Kw, Mrows, NKH * HD, DM);
    gemm_f32<<<dim3((NKH * HD) / 64, Mrows / 64), 256, 0, stream>>>(x, wv, Vw, Mrows, NKH * HD, DM);

    // RoPE on Q and K (in place)
    {
        const int totQ = Mrows * NH * 32;   // 2,097,152
        const int totK = Mrows * NKH * 32;  //   524,288
        rope_k<<<(totQ + 255) / 256, 256, 0, stream>>>(Qw, cosp, sinp, NH, totQ);
        rope_k<<<(totK + 255) / 256, 256, 0, stream>>>(Kw, cosp, sinp, NKH, totK);
    }

    // causal GQA flash attention
    flash_attn<<<dim3(SLEN / 64, NH, BATCH), 256, 0, stream>>>(Qw, Kw, Vw, Ow);

    // output projection
    gemm_f32<<<dim3(DM / 64, Mrows / 64), 256, 0, stream>>>(Ow, wo, out, Mrows, DM, DM);
}

// Round 2
// 579.670 us; speedup vs baseline: 3.0241x; 3.0241x over previous
//
#include <hip/hip_runtime.h>
#include <hip/hip_bf16.h>

// Problem constants
#define BATCH 2
#define SLEN  2048
#define DM    1024
#define NH    16
#define NKH   4
#define HD    64

typedef __attribute__((ext_vector_type(8))) short short8;   // 8 bf16 = 4 VGPRs (MFMA A/B frag)
typedef __attribute__((ext_vector_type(4))) float f32x4;    // MFMA C/D frag

// fp32 -> bf16 (RNE) as raw bits
static __device__ __forceinline__ short f2bf(float x) {
    unsigned u = __float_as_uint(x);
    u += 0x7fffu + ((u >> 16) & 1u);
    return (short)(u >> 16);
}

// ---------------------------------------------------------------------------
// Generic fp32 tiled GEMM: C[M,N] = A[M,K] @ B[K,N]  (unchanged from R1)
// ---------------------------------------------------------------------------
__global__ __launch_bounds__(256) void gemm_f32(
    const float* __restrict__ A, const float* __restrict__ Bm,
    float* __restrict__ C, int M, int N, int Kd)
{
    const int t  = threadIdx.x;
    const int tx = t & 15;
    const int ty = t >> 4;
    const int n0 = blockIdx.x * 64;
    const int m0 = blockIdx.y * 64;

    __shared__ float As[16][65];
    __shared__ float Bs[16][64];

    float acc[4][4];
#pragma unroll
    for (int i = 0; i < 4; ++i)
#pragma unroll
        for (int j = 0; j < 4; ++j) acc[i][j] = 0.f;

    for (int kt = 0; kt < Kd; kt += 16) {
        {
            const int m  = t >> 2;
            const int kc = (t & 3) * 4;
            const float4 av = *(const float4*)(A + (size_t)(m0 + m) * Kd + kt + kc);
            As[kc + 0][m] = av.x; As[kc + 1][m] = av.y;
            As[kc + 2][m] = av.z; As[kc + 3][m] = av.w;
            const int kr = t >> 4;
            const int nc = (t & 15) * 4;
            *(float4*)&Bs[kr][nc] =
                *(const float4*)(Bm + (size_t)(kt + kr) * N + n0 + nc);
        }
        __syncthreads();
#pragma unroll
        for (int kk = 0; kk < 16; ++kk) {
            const float a0 = As[kk][ty * 4 + 0];
            const float a1 = As[kk][ty * 4 + 1];
            const float a2 = As[kk][ty * 4 + 2];
            const float a3 = As[kk][ty * 4 + 3];
            const float4 b = *(const float4*)&Bs[kk][tx * 4];
            acc[0][0] += a0 * b.x; acc[0][1] += a0 * b.y; acc[0][2] += a0 * b.z; acc[0][3] += a0 * b.w;
            acc[1][0] += a1 * b.x; acc[1][1] += a1 * b.y; acc[1][2] += a1 * b.z; acc[1][3] += a1 * b.w;
            acc[2][0] += a2 * b.x; acc[2][1] += a2 * b.y; acc[2][2] += a2 * b.z; acc[2][3] += a2 * b.w;
            acc[3][0] += a3 * b.x; acc[3][1] += a3 * b.y; acc[3][2] += a3 * b.z; acc[3][3] += a3 * b.w;
        }
        __syncthreads();
    }

#pragma unroll
    for (int i = 0; i < 4; ++i) {
        float4 o;
        o.x = acc[i][0]; o.y = acc[i][1]; o.z = acc[i][2]; o.w = acc[i][3];
        *(float4*)(C + (size_t)(m0 + ty * 4 + i) * N + n0 + tx * 4) = o;
    }
}

// ---------------------------------------------------------------------------
// Fused RoPE + fp32->bf16 convert. P fp32 [B,S,nh,64] -> Pb bf16 same layout.
// scale folded in (Q gets 1/sqrt(HD), K gets 1.0).
// ---------------------------------------------------------------------------
__global__ void rope_cvt(const float* __restrict__ P, short* __restrict__ Pb,
                         const float* __restrict__ cosp, const float* __restrict__ sinp,
                         int nh, float scale, int total)
{
    const int idx = blockIdx.x * blockDim.x + threadIdx.x;
    if (idx >= total) return;
    const int d  = idx & 31;
    const int h  = (idx >> 5) % nh;
    const int bs = (idx >> 5) / nh;
    const int s  = bs & (SLEN - 1);
    const size_t base = (size_t)bs * (nh * HD) + h * HD;
    const float cv = cosp[s * HD + d];
    const float sv = sinp[s * HD + d];
    const float x0 = P[base + d];
    const float x1 = P[base + d + 32];
    Pb[base + d]      = f2bf((x0 * cv - x1 * sv) * scale);
    Pb[base + d + 32] = f2bf((x1 * cv + x0 * sv) * scale);
}

// ---------------------------------------------------------------------------
// V transpose + convert: Vw fp32 [B,S,KH,64] -> Vt bf16 [B,KH,64(d),S(keys)]
// so the flash kernel's PV B-operand (contiguous keys per d) loads directly.
// ---------------------------------------------------------------------------
__global__ __launch_bounds__(256) void vtrans_cvt(
    const float* __restrict__ V, short* __restrict__ Vt)
{
    const int st = blockIdx.x;    // s tile (64)
    const int kh = blockIdx.y;
    const int b  = blockIdx.z;
    const int t  = threadIdx.x;
    const int s0 = st * 64;
    __shared__ float tile[64][65];

#pragma unroll
    for (int i = 0; i < 4; ++i) {
        const int idx = t + i * 256;
        const int r = idx >> 4;
        const int c = (idx & 15) * 4;
        const float4 v = *(const float4*)(V + ((size_t)(b * SLEN + s0 + r)) * (NKH * HD) + kh * HD + c);
        tile[r][c + 0] = v.x; tile[r][c + 1] = v.y;
        tile[r][c + 2] = v.z; tile[r][c + 3] = v.w;
    }
    __syncthreads();

#pragma unroll
    for (int i = 0; i < 2; ++i) {
        const int idx = t + i * 256;
        const int d  = idx >> 3;
        const int sc = (idx & 7) * 8;
        __align__(16) short o[8];
#pragma unroll
        for (int j = 0; j < 8; ++j) o[j] = f2bf(tile[sc + j][d]);
        *(int4*)(Vt + ((size_t)((b * NKH + kh) * HD + d)) * SLEN + s0 + sc) = *(const int4*)o;
    }
}

// ---------------------------------------------------------------------------
// Flash attention on MFMA bf16 16x16x32. Causal, GQA.
// Block = 256 threads (4 waves). Tile 64 q x 64 k; wave w owns queries w*16..+16.
// Q pre-scaled by 1/8. LDS rows padded to 72 bf16 (144 B) -> <=2-way banks.
// ---------------------------------------------------------------------------
#define PSTR 72

__global__ __launch_bounds__(256) void flash_mfma(
    const short* __restrict__ Qb,   // [B,S,NH,64] bf16
    const short* __restrict__ Kb,   // [B,S,NKH,64] bf16
    const short* __restrict__ Vt,   // [B,NKH,64,S] bf16 (V^T)
    float* __restrict__ O)          // [B,S,NH,64] fp32
{
    const int qt   = gridDim.x - 1 - blockIdx.x;  // heavy (late) q-tiles first
    const int h    = blockIdx.y;
    const int b    = blockIdx.z;
    const int kh   = h >> 2;
    const int t    = threadIdx.x;
    const int lane = t & 63;
    const int w    = t >> 6;
    const int q0   = qt * 64;
    const int l15  = lane & 15;
    const int l4   = lane >> 4;

    __shared__ __align__(16) short Qs[64 * PSTR];
    __shared__ __align__(16) short Ks[64 * PSTR];
    __shared__ __align__(16) short Vs[64 * PSTR];      // V^T tile: [d][key]
    __shared__ __align__(16) short Ps[4][16 * PSTR];   // per-wave P strip [q][key]

    // Load Q tile (64 x 64 bf16), 16B chunks
#pragma unroll
    for (int i = 0; i < 2; ++i) {
        const int idx = t + i * 256;
        const int r = idx >> 3, c = (idx & 7) * 8;
        *(int4*)&Qs[r * PSTR + c] =
            *(const int4*)(Qb + ((size_t)((b * SLEN + q0 + r) * NH + h)) * HD + c);
    }

    f32x4 acc[4];
#pragma unroll
    for (int nt = 0; nt < 4; ++nt) acc[nt] = (f32x4){0.f, 0.f, 0.f, 0.f};
    float m_run[4], l_run[4];
#pragma unroll
    for (int r = 0; r < 4; ++r) { m_run[r] = -1e30f; l_run[r] = 0.f; }

    for (int kt = 0; kt <= qt; ++kt) {
        const int k0 = kt * 64;
        __syncthreads();  // previous iteration's frag reads done
#pragma unroll
        for (int i = 0; i < 2; ++i) {
            const int idx = t + i * 256;
            const int r = idx >> 3, c = (idx & 7) * 8;
            *(int4*)&Ks[r * PSTR + c] =
                *(const int4*)(Kb + ((size_t)((b * SLEN + k0 + r) * NKH + kh)) * HD + c);
            *(int4*)&Vs[r * PSTR + c] =
                *(const int4*)(Vt + ((size_t)((b * NKH + kh) * HD + r)) * SLEN + k0 + c);
        }
        __syncthreads();

        // ---- QK^T: 8 MFMA per wave ----
        f32x4 sf[4];
#pragma unroll
        for (int f = 0; f < 4; ++f) sf[f] = (f32x4){0.f, 0.f, 0.f, 0.f};
#pragma unroll
        for (int ks = 0; ks < 2; ++ks) {
            const short8 aq = *(const short8*)&Qs[(w * 16 + l15) * PSTR + ks * 32 + l4 * 8];
#pragma unroll
            for (int f = 0; f < 4; ++f) {
                const short8 bk = *(const short8*)&Ks[(f * 16 + l15) * PSTR + ks * 32 + l4 * 8];
                sf[f] = __builtin_amdgcn_mfma_f32_16x16x32_bf16(aq, bk, sf[f], 0, 0, 0);
            }
        }

        // causal mask (only the diagonal tile can violate)
        if (kt == qt) {
#pragma unroll
            for (int f = 0; f < 4; ++f)
#pragma unroll
                for (int r = 0; r < 4; ++r)
                    if (f * 16 + l15 > w * 16 + l4 * 4 + r) sf[f][r] = -1e30f;
        }

        // ---- online softmax (stats in regs; rows live on 16-lane groups) ----
        float mloc[4], psum[4], alpha[4];
#pragma unroll
        for (int r = 0; r < 4; ++r)
            mloc[r] = fmaxf(fmaxf(sf[0][r], sf[1][r]), fmaxf(sf[2][r], sf[3][r]));
#pragma unroll
        for (int off = 1; off < 16; off <<= 1)
#pragma unroll
            for (int r = 0; r < 4; ++r)
                mloc[r] = fmaxf(mloc[r], __shfl_xor(mloc[r], off));
#pragma unroll
        for (int r = 0; r < 4; ++r) {
            const float mn = fmaxf(m_run[r], mloc[r]);
            alpha[r] = __expf(m_run[r] - mn);
            m_run[r] = mn;
            psum[r] = 0.f;
        }
#pragma unroll
        for (int f = 0; f < 4; ++f)
#pragma unroll
            for (int r = 0; r < 4; ++r) {
                const float p = __expf(sf[f][r] - m_run[r]);
                psum[r] += p;
                Ps[w][(l4 * 4 + r) * PSTR + f * 16 + l15] = f2bf(p);
            }
#pragma unroll
        for (int off = 1; off < 16; off <<= 1)
#pragma unroll
            for (int r = 0; r < 4; ++r)
                psum[r] += __shfl_xor(psum[r], off);
#pragma unroll
        for (int r = 0; r < 4; ++r) l_run[r] = l_run[r] * alpha[r] + psum[r];
#pragma unroll
        for (int nt = 0; nt < 4; ++nt)
#pragma unroll
            for (int r = 0; r < 4; ++r) acc[nt][r] *= alpha[r];

        // ---- PV: 8 MFMA per wave (Ps is wave-private; no barrier needed) ----
#pragma unroll
        for (int ks = 0; ks < 2; ++ks) {
            const short8 ap = *(const short8*)&Ps[w][l15 * PSTR + ks * 32 + l4 * 8];
#pragma unroll
            for (int nt = 0; nt < 4; ++nt) {
                const short8 bv = *(const short8*)&Vs[(nt * 16 + l15) * PSTR + ks * 32 + l4 * 8];
                acc[nt] = __builtin_amdgcn_mfma_f32_16x16x32_bf16(ap, bv, acc[nt], 0, 0, 0);
            }
        }
    }

    // epilogue: O = acc / l
    float rl[4];
#pragma unroll
    for (int r = 0; r < 4; ++r) rl[r] = 1.f / l_run[r];
#pragma unroll
    for (int nt = 0; nt < 4; ++nt)
#pragma unroll
        for (int r = 0; r < 4; ++r) {
            const int q = w * 16 + l4 * 4 + r;
            O[((size_t)((b * SLEN + q0 + q) * NH + h)) * HD + nt * 16 + l15] = acc[nt][r] * rl[r];
        }
}

// ---------------------------------------------------------------------------
extern "C" void kernel_launch(void* const* d_in, const int* in_sizes, int n_in,
                              void* d_out, int out_size, void* d_ws, size_t ws_size,
                              hipStream_t stream) {
    const float* x    = (const float*)d_in[0];
    const float* cosp = (const float*)d_in[1];
    const float* sinp = (const float*)d_in[2];
    const float* wq   = (const float*)d_in[3];
    const float* wk   = (const float*)d_in[4];
    const float* wv   = (const float*)d_in[5];
    const float* wo   = (const float*)d_in[6];
    float* out = (float*)d_out;

    const int Mrows = BATCH * SLEN;   // 4096

    // workspace: Qw(16M) Kw(4M) Vw(4M) | Qb(8M) Kb(2M) Vt(2M); Ow aliases Qw
    float* Qw = (float*)d_ws;
    float* Kw = Qw + (size_t)Mrows * 1024;
    float* Vw = Kw + (size_t)Mrows * 256;
    short* Qb = (short*)(Vw + (size_t)Mrows * 256);
    short* Kb = Qb + (size_t)Mrows * 1024;
    short* Vt = Kb + (size_t)Mrows * 256;
    float* Ow = Qw;   // flash no longer needs Qw (it reads Qb)

    // QKV projections (fp32)
    gemm_f32<<<dim3((NH * HD) / 64, Mrows / 64), 256, 0, stream>>>(x, wq, Qw, Mrows, NH * HD, DM);
    gemm_f32<<<dim3((NKH * HD) / 64, Mrows / 64), 256, 0, stream>>>(x, wk, Kw, Mrows, NKH * HD, DM);
    gemm_f32<<<dim3((NKH * HD) / 64, Mrows / 64), 256, 0, stream>>>(x, wv, Vw, Mrows, NKH * HD, DM);

    // RoPE + bf16 convert (Q pre-scaled by 1/sqrt(64))
    {
        const int totQ = Mrows * NH * 32;
        const int totK = Mrows * NKH * 32;
        rope_cvt<<<(totQ + 255) / 256, 256, 0, stream>>>(Qw, Qb, cosp, sinp, NH, 0.125f, totQ);
        rope_cvt<<<(totK + 255) / 256, 256, 0, stream>>>(Kw, Kb, cosp, sinp, NKH, 1.0f, totK);
    }

    // V transpose + convert
    vtrans_cvt<<<dim3(SLEN / 64, NKH, BATCH), 256, 0, stream>>>(Vw, Vt);

    // causal GQA flash attention on MFMA
    flash_mfma<<<dim3(SLEN / 64, NH, BATCH), 256, 0, stream>>>(Qb, Kb, Vt, Ow);

    // output projection (fp32)
    gemm_f32<<<dim3(DM / 64, Mrows / 64), 256, 0, stream>>>(Ow, wo, out, Mrows, DM, DM);
}

// Round 3
// 263.906 us; speedup vs baseline: 6.6424x; 2.1965x over previous
//
#include <hip/hip_runtime.h>
#include <hip/hip_bf16.h>

// Problem constants
#define BATCH 2
#define SLEN  2048
#define DM    1024
#define NH    16
#define NKH   4
#define HD    64

typedef __attribute__((ext_vector_type(8))) short short8;   // 8 bf16 (MFMA A/B frag)
typedef __attribute__((ext_vector_type(4))) float f32x4;    // MFMA C/D frag

// fp32 -> bf16 (RNE) as raw bits
static __device__ __forceinline__ short f2bf(float x) {
    unsigned u = __float_as_uint(x);
    u += 0x7fffu + ((u >> 16) & 1u);
    return (short)(u >> 16);
}

// async global->LDS, 16 bytes per lane. LDS dest must be uniform base + lane*16.
static __device__ __forceinline__ void ldg_lds16(const short* g, short* l) {
    __builtin_amdgcn_global_load_lds(
        (const __attribute__((address_space(1))) unsigned int*)(const void*)g,
        (__attribute__((address_space(3))) unsigned int*)(void*)l,
        16, 0, 0);
}

// ---------------------------------------------------------------------------
// x fp32 -> bf16 (8 elems/thread)
// ---------------------------------------------------------------------------
__global__ void cvt_bf16(const float* __restrict__ X, short* __restrict__ Xb, int total8)
{
    const int i = blockIdx.x * blockDim.x + threadIdx.x;
    if (i >= total8) return;
    const float4 v0 = ((const float4*)X)[i * 2];
    const float4 v1 = ((const float4*)X)[i * 2 + 1];
    __align__(16) short o[8];
    o[0] = f2bf(v0.x); o[1] = f2bf(v0.y); o[2] = f2bf(v0.z); o[3] = f2bf(v0.w);
    o[4] = f2bf(v1.x); o[5] = f2bf(v1.y); o[6] = f2bf(v1.z); o[7] = f2bf(v1.w);
    ((int4*)Xb)[i] = *(const int4*)o;
}

// ---------------------------------------------------------------------------
// Weight transpose + convert: W fp32 [1024(K)][Nc] -> T bf16 rows (rowoff+n)[1024]
// ---------------------------------------------------------------------------
__global__ __launch_bounds__(256) void wtrans(
    const float* __restrict__ W, short* __restrict__ T, int Nc, int rowoff)
{
    const int kt = blockIdx.x * 64;
    const int nt = blockIdx.y * 64;
    const int t  = threadIdx.x;
    __shared__ float tile[64][65];

#pragma unroll
    for (int i = 0; i < 4; ++i) {
        const int r = (t >> 4) + i * 16;       // k row in tile
        const int c = (t & 15) * 4;            // n col
        const float4 v = *(const float4*)(W + (size_t)(kt + r) * Nc + nt + c);
        tile[r][c + 0] = v.x; tile[r][c + 1] = v.y;
        tile[r][c + 2] = v.z; tile[r][c + 3] = v.w;
    }
    __syncthreads();
#pragma unroll
    for (int i = 0; i < 2; ++i) {
        const int rr = (t >> 3) + i * 32;      // n row of output
        const int cc = (t & 7) * 8;            // k col of output
        __align__(16) short o[8];
#pragma unroll
        for (int j = 0; j < 8; ++j) o[j] = f2bf(tile[cc + j][rr]);
        *(int4*)(T + (size_t)(rowoff + nt + rr) * 1024 + kt + cc) = *(const int4*)o;
    }
}

// ---------------------------------------------------------------------------
// bf16 MFMA GEMM: C[M,N] = A[M,K] * Bt[N,K]^T.  m97 structure: 128x128 tile,
// BK=32, 256 threads (4 waves, each 64x64 = 4x4 MFMA tiles), global_load_lds.
// MODE 0: fused QKV epilogue — RoPE on Q (scaled 1/8) and K in registers,
//         scatter to Qb [B,S,NH,64], Kb [B,S,NKH,64], Vt [B,NKH,64,S] (bf16).
// MODE 1: plain fp32 C output.
// ---------------------------------------------------------------------------
template<int MODE>
__global__ __launch_bounds__(256) void gemm_abt(
    const short* __restrict__ A, const short* __restrict__ Bt,
    int M, int N, int K,
    float* __restrict__ Cf,
    short* __restrict__ Qb, short* __restrict__ Kb, short* __restrict__ Vt,
    const float* __restrict__ cosp, const float* __restrict__ sinp)
{
    const int t    = threadIdx.x;
    const int lane = t & 63;
    const int w    = t >> 6;
    const int l15  = lane & 15;
    const int l4   = lane >> 4;
    const int n0   = blockIdx.x * 128;
    const int m0   = blockIdx.y * 128;
    const int wm   = (w & 1) * 64;
    const int wn   = (w >> 1) * 64;

    __shared__ __align__(16) short As[128 * 32];
    __shared__ __align__(16) short Bs[128 * 32];

    f32x4 acc[4][4];
#pragma unroll
    for (int i = 0; i < 4; ++i)
#pragma unroll
        for (int j = 0; j < 4; ++j) acc[i][j] = (f32x4){0.f, 0.f, 0.f, 0.f};

    for (int kt = 0; kt < K; kt += 32) {
        __syncthreads();   // previous iteration's frag reads done
#pragma unroll
        for (int i = 0; i < 2; ++i) {
            const int chunk = i * 256 + t;           // 16B chunk, 0..511
            const int r = chunk >> 2;                // tile row
            const int c = (chunk & 3) * 8;           // bf16 col in row
            ldg_lds16(A  + (size_t)(m0 + r) * K + kt + c, &As[chunk * 8]);
            ldg_lds16(Bt + (size_t)(n0 + r) * K + kt + c, &Bs[chunk * 8]);
        }
        __syncthreads();   // drains vmcnt -> LDS visible

        short8 af[4], bf[4];
#pragma unroll
        for (int i = 0; i < 4; ++i)
            af[i] = *(const short8*)&As[(wm + i * 16 + l15) * 32 + l4 * 8];
#pragma unroll
        for (int j = 0; j < 4; ++j)
            bf[j] = *(const short8*)&Bs[(wn + j * 16 + l15) * 32 + l4 * 8];
#pragma unroll
        for (int i = 0; i < 4; ++i)
#pragma unroll
            for (int j = 0; j < 4; ++j)
                acc[i][j] = __builtin_amdgcn_mfma_f32_16x16x32_bf16(af[i], bf[j], acc[i][j], 0, 0, 0);
    }

    if (MODE == 1) {
        // plain fp32 C
#pragma unroll
        for (int i = 0; i < 4; ++i)
#pragma unroll
            for (int j = 0; j < 4; ++j)
#pragma unroll
                for (int r = 0; r < 4; ++r) {
                    const int m = m0 + wm + i * 16 + l4 * 4 + r;
                    const int n = n0 + wn + j * 16 + l15;
                    Cf[(size_t)m * N + n] = acc[i][j][r];
                }
        return;
    }

    // MODE 0: fused QKV epilogue. This wave's 64-col span = exactly one head.
    const int colbase = n0 + wn;                 // multiple of 64
    if (colbase < 1024) {
        const int h = colbase >> 6;              // Q head
#pragma unroll
        for (int i = 0; i < 4; ++i)
#pragma unroll
            for (int r = 0; r < 4; ++r) {
                const int m = m0 + wm + i * 16 + l4 * 4 + r;
                const int b = m >> 11, s = m & (SLEN - 1);
                short* dst = Qb + (((size_t)(b * SLEN + s) * NH + h) << 6);
#pragma unroll
                for (int j = 0; j < 2; ++j) {
                    const int d = j * 16 + l15;  // < 32
                    const float cv = cosp[s * HD + d];
                    const float sv = sinp[s * HD + d];
                    const float a0 = acc[i][j][r];
                    const float a1 = acc[i][j + 2][r];
                    dst[d]      = f2bf((a0 * cv - a1 * sv) * 0.125f);
                    dst[d + 32] = f2bf((a1 * cv + a0 * sv) * 0.125f);
                }
            }
    } else if (colbase < 1280) {
        const int kh = (colbase - 1024) >> 6;    // K head
#pragma unroll
        for (int i = 0; i < 4; ++i)
#pragma unroll
            for (int r = 0; r < 4; ++r) {
                const int m = m0 + wm + i * 16 + l4 * 4 + r;
                const int b = m >> 11, s = m & (SLEN - 1);
                short* dst = Kb + (((size_t)(b * SLEN + s) * NKH + kh) << 6);
#pragma unroll
                for (int j = 0; j < 2; ++j) {
                    const int d = j * 16 + l15;
                    const float cv = cosp[s * HD + d];
                    const float sv = sinp[s * HD + d];
                    const float a0 = acc[i][j][r];
                    const float a1 = acc[i][j + 2][r];
                    dst[d]      = f2bf(a0 * cv - a1 * sv);
                    dst[d + 32] = f2bf(a1 * cv + a0 * sv);
                }
            }
    } else {
        const int kh = (colbase - 1280) >> 6;    // V head -> transposed store
#pragma unroll
        for (int i = 0; i < 4; ++i)
#pragma unroll
            for (int r = 0; r < 4; ++r) {
                const int m = m0 + wm + i * 16 + l4 * 4 + r;
                const int b = m >> 11, s = m & (SLEN - 1);
#pragma unroll
                for (int j = 0; j < 4; ++j) {
                    const int d = j * 16 + l15;
                    Vt[((size_t)((b * NKH + kh) * HD + d)) * SLEN + s] = f2bf(acc[i][j][r]);
                }
            }
    }
}

// ---------------------------------------------------------------------------
// Flash attention on MFMA bf16 16x16x32. Causal, GQA. (R2 kernel; epilogue
// now writes bf16 so the wo GEMM reads bf16 A.)
// ---------------------------------------------------------------------------
#define PSTR 72

__global__ __launch_bounds__(256) void flash_mfma(
    const short* __restrict__ Qb,   // [B,S,NH,64] bf16 (pre-scaled 1/8)
    const short* __restrict__ Kb,   // [B,S,NKH,64] bf16
    const short* __restrict__ Vt,   // [B,NKH,64,S] bf16 (V^T)
    short* __restrict__ O)          // [B,S,NH,64] bf16
{
    const int qt   = gridDim.x - 1 - blockIdx.x;  // heavy q-tiles first
    const int h    = blockIdx.y;
    const int b    = blockIdx.z;
    const int kh   = h >> 2;
    const int t    = threadIdx.x;
    const int lane = t & 63;
    const int w    = t >> 6;
    const int q0   = qt * 64;
    const int l15  = lane & 15;
    const int l4   = lane >> 4;

    __shared__ __align__(16) short Qs[64 * PSTR];
    __shared__ __align__(16) short Ks[64 * PSTR];
    __shared__ __align__(16) short Vs[64 * PSTR];
    __shared__ __align__(16) short Ps[4][16 * PSTR];

#pragma unroll
    for (int i = 0; i < 2; ++i) {
        const int idx = t + i * 256;
        const int r = idx >> 3, c = (idx & 7) * 8;
        *(int4*)&Qs[r * PSTR + c] =
            *(const int4*)(Qb + ((size_t)((b * SLEN + q0 + r) * NH + h)) * HD + c);
    }

    f32x4 acc[4];
#pragma unroll
    for (int nt = 0; nt < 4; ++nt) acc[nt] = (f32x4){0.f, 0.f, 0.f, 0.f};
    float m_run[4], l_run[4];
#pragma unroll
    for (int r = 0; r < 4; ++r) { m_run[r] = -1e30f; l_run[r] = 0.f; }

    for (int kt = 0; kt <= qt; ++kt) {
        const int k0 = kt * 64;
        __syncthreads();
#pragma unroll
        for (int i = 0; i < 2; ++i) {
            const int idx = t + i * 256;
            const int r = idx >> 3, c = (idx & 7) * 8;
            *(int4*)&Ks[r * PSTR + c] =
                *(const int4*)(Kb + ((size_t)((b * SLEN + k0 + r) * NKH + kh)) * HD + c);
            *(int4*)&Vs[r * PSTR + c] =
                *(const int4*)(Vt + ((size_t)((b * NKH + kh) * HD + r)) * SLEN + k0 + c);
        }
        __syncthreads();

        // ---- QK^T ----
        f32x4 sf[4];
#pragma unroll
        for (int f = 0; f < 4; ++f) sf[f] = (f32x4){0.f, 0.f, 0.f, 0.f};
#pragma unroll
        for (int ks = 0; ks < 2; ++ks) {
            const short8 aq = *(const short8*)&Qs[(w * 16 + l15) * PSTR + ks * 32 + l4 * 8];
#pragma unroll
            for (int f = 0; f < 4; ++f) {
                const short8 bk = *(const short8*)&Ks[(f * 16 + l15) * PSTR + ks * 32 + l4 * 8];
                sf[f] = __builtin_amdgcn_mfma_f32_16x16x32_bf16(aq, bk, sf[f], 0, 0, 0);
            }
        }

        if (kt == qt) {
#pragma unroll
            for (int f = 0; f < 4; ++f)
#pragma unroll
                for (int r = 0; r < 4; ++r)
                    if (f * 16 + l15 > w * 16 + l4 * 4 + r) sf[f][r] = -1e30f;
        }

        // ---- online softmax ----
        float mloc[4], psum[4], alpha[4];
#pragma unroll
        for (int r = 0; r < 4; ++r)
            mloc[r] = fmaxf(fmaxf(sf[0][r], sf[1][r]), fmaxf(sf[2][r], sf[3][r]));
#pragma unroll
        for (int off = 1; off < 16; off <<= 1)
#pragma unroll
            for (int r = 0; r < 4; ++r)
                mloc[r] = fmaxf(mloc[r], __shfl_xor(mloc[r], off));
#pragma unroll
        for (int r = 0; r < 4; ++r) {
            const float mn = fmaxf(m_run[r], mloc[r]);
            alpha[r] = __expf(m_run[r] - mn);
            m_run[r] = mn;
            psum[r] = 0.f;
        }
#pragma unroll
        for (int f = 0; f < 4; ++f)
#pragma unroll
            for (int r = 0; r < 4; ++r) {
                const float p = __expf(sf[f][r] - m_run[r]);
                psum[r] += p;
                Ps[w][(l4 * 4 + r) * PSTR + f * 16 + l15] = f2bf(p);
            }
#pragma unroll
        for (int off = 1; off < 16; off <<= 1)
#pragma unroll
            for (int r = 0; r < 4; ++r)
                psum[r] += __shfl_xor(psum[r], off);
#pragma unroll
        for (int r = 0; r < 4; ++r) l_run[r] = l_run[r] * alpha[r] + psum[r];
#pragma unroll
        for (int nt = 0; nt < 4; ++nt)
#pragma unroll
            for (int r = 0; r < 4; ++r) acc[nt][r] *= alpha[r];

        // ---- PV ----
#pragma unroll
        for (int ks = 0; ks < 2; ++ks) {
            const short8 ap = *(const short8*)&Ps[w][l15 * PSTR + ks * 32 + l4 * 8];
#pragma unroll
            for (int nt = 0; nt < 4; ++nt) {
                const short8 bv = *(const short8*)&Vs[(nt * 16 + l15) * PSTR + ks * 32 + l4 * 8];
                acc[nt] = __builtin_amdgcn_mfma_f32_16x16x32_bf16(ap, bv, acc[nt], 0, 0, 0);
            }
        }
    }

    float rl[4];
#pragma unroll
    for (int r = 0; r < 4; ++r) rl[r] = 1.f / l_run[r];
#pragma unroll
    for (int nt = 0; nt < 4; ++nt)
#pragma unroll
        for (int r = 0; r < 4; ++r) {
            const int q = w * 16 + l4 * 4 + r;
            O[((size_t)((b * SLEN + q0 + q) * NH + h)) * HD + nt * 16 + l15] =
                f2bf(acc[nt][r] * rl[r]);
        }
}

// ---------------------------------------------------------------------------
extern "C" void kernel_launch(void* const* d_in, const int* in_sizes, int n_in,
                              void* d_out, int out_size, void* d_ws, size_t ws_size,
                              hipStream_t stream) {
    const float* x    = (const float*)d_in[0];
    const float* cosp = (const float*)d_in[1];
    const float* sinp = (const float*)d_in[2];
    const float* wq   = (const float*)d_in[3];
    const float* wk   = (const float*)d_in[4];
    const float* wv   = (const float*)d_in[5];
    const float* wo   = (const float*)d_in[6];
    float* out = (float*)d_out;

    const int Mrows = BATCH * SLEN;   // 4096

    // workspace (bf16 elements): xb/Ob alias (xb dead before Ob written)
    short* xb = (short*)d_ws;                         // 4096*1024
    short* Ob = xb;                                   // alias
    short* wT = xb + (size_t)Mrows * 1024;            // 2560*1024 (QKV^T rows 0..1535, wo^T rows 1536..2559)
    short* Qb = wT + (size_t)2560 * 1024;             // 4096*1024
    short* Kb = Qb + (size_t)Mrows * 1024;            // 4096*256
    short* Vt = Kb + (size_t)Mrows * 256;             // 4096*256

    // x -> bf16
    cvt_bf16<<<(Mrows * DM / 8 + 255) / 256, 256, 0, stream>>>(x, xb, Mrows * DM / 8);

    // weight transposes -> bf16 [N][K]
    wtrans<<<dim3(16, 16), 256, 0, stream>>>(wq, wT, 1024, 0);
    wtrans<<<dim3(16, 4),  256, 0, stream>>>(wk, wT, 256, 1024);
    wtrans<<<dim3(16, 4),  256, 0, stream>>>(wv, wT, 256, 1280);
    wtrans<<<dim3(16, 16), 256, 0, stream>>>(wo, wT, 1024, 1536);

    // fused QKV projection + RoPE + layout scatter (N=1536)
    gemm_abt<0><<<dim3(1536 / 128, Mrows / 128), 256, 0, stream>>>(
        xb, wT, Mrows, 1536, DM, nullptr, Qb, Kb, Vt, cosp, sinp);

    // causal GQA flash attention
    flash_mfma<<<dim3(SLEN / 64, NH, BATCH), 256, 0, stream>>>(Qb, Kb, Vt, Ob);

    // output projection (fp32 out)
    gemm_abt<1><<<dim3(DM / 128, Mrows / 128), 256, 0, stream>>>(
        Ob, wT + (size_t)1536 * 1024, Mrows, DM, DM, out,
        nullptr, nullptr, nullptr, nullptr, nullptr);
}

// Round 5
// 229.812 us; speedup vs baseline: 7.6278x; 1.1484x over previous
//
#include <hip/hip_runtime.h>
#include <hip/hip_bf16.h>

// Problem constants
#define BATCH 2
#define SLEN  2048
#define DM    1024
#define NH    16
#define NKH   4
#define HD    64

typedef __attribute__((ext_vector_type(8))) short short8;   // 8 bf16 (MFMA A/B frag)
typedef __attribute__((ext_vector_type(4))) float f32x4;    // MFMA C/D frag

// fp32 -> bf16 (RNE) as raw bits
static __device__ __forceinline__ short f2bf(float x) {
    unsigned u = __float_as_uint(x);
    u += 0x7fffu + ((u >> 16) & 1u);
    return (short)(u >> 16);
}

// async global->LDS, 16 bytes per lane. LDS dest must be uniform base + lane*16.
static __device__ __forceinline__ void ldg_lds16(const short* g, short* l) {
    __builtin_amdgcn_global_load_lds(
        (const __attribute__((address_space(1))) unsigned int*)(const void*)g,
        (__attribute__((address_space(3))) unsigned int*)(void*)l,
        16, 0, 0);
}

// log2(e)/8 : folds both the 1/sqrt(HD) score scale and the exp->exp2
// conversion into the Q projection epilogue.
#define QSCALE 0.1803368801f

// ---------------------------------------------------------------------------
// x fp32 -> bf16 (8 elems/thread)
// ---------------------------------------------------------------------------
__global__ void cvt_bf16(const float* __restrict__ X, short* __restrict__ Xb, int total8)
{
    const int i = blockIdx.x * blockDim.x + threadIdx.x;
    if (i >= total8) return;
    const float4 v0 = ((const float4*)X)[i * 2];
    const float4 v1 = ((const float4*)X)[i * 2 + 1];
    __align__(16) short o[8];
    o[0] = f2bf(v0.x); o[1] = f2bf(v0.y); o[2] = f2bf(v0.z); o[3] = f2bf(v0.w);
    o[4] = f2bf(v1.x); o[5] = f2bf(v1.y); o[6] = f2bf(v1.z); o[7] = f2bf(v1.w);
    ((int4*)Xb)[i] = *(const int4*)o;
}

// ---------------------------------------------------------------------------
// All four weight transposes in one launch. W fp32 [1024(K)][Nc] -> T bf16
// rows (rowoff+n)[1024]. grid (16 k-tiles, 40 n-tiles).
// ---------------------------------------------------------------------------
__global__ __launch_bounds__(256) void wtrans_all(
    const float* __restrict__ wq, const float* __restrict__ wk,
    const float* __restrict__ wv, const float* __restrict__ wo,
    short* __restrict__ T)
{
    const int by = blockIdx.y;
    const float* W; int Nc, rowoff, ntile;
    if (by < 16)      { W = wq; Nc = 1024; rowoff = 0;    ntile = by; }
    else if (by < 20) { W = wk; Nc = 256;  rowoff = 1024; ntile = by - 16; }
    else if (by < 24) { W = wv; Nc = 256;  rowoff = 1280; ntile = by - 20; }
    else              { W = wo; Nc = 1024; rowoff = 1536; ntile = by - 24; }
    const int kt = blockIdx.x * 64;
    const int nt = ntile * 64;
    const int t  = threadIdx.x;
    __shared__ float tile[64][65];

#pragma unroll
    for (int i = 0; i < 4; ++i) {
        const int r = (t >> 4) + i * 16;
        const int c = (t & 15) * 4;
        const float4 v = *(const float4*)(W + (size_t)(kt + r) * Nc + nt + c);
        tile[r][c + 0] = v.x; tile[r][c + 1] = v.y;
        tile[r][c + 2] = v.z; tile[r][c + 3] = v.w;
    }
    __syncthreads();
#pragma unroll
    for (int i = 0; i < 2; ++i) {
        const int rr = (t >> 3) + i * 32;
        const int cc = (t & 7) * 8;
        __align__(16) short o[8];
#pragma unroll
        for (int j = 0; j < 8; ++j) o[j] = f2bf(tile[cc + j][rr]);
        *(int4*)(T + (size_t)(rowoff + nt + rr) * 1024 + kt + cc) = *(const int4*)o;
    }
}

// ---------------------------------------------------------------------------
// bf16 MFMA GEMM: C[M,N] = A[M,K] * Bt[N,K]^T.  128x128 tile, BK=32,
// 256 threads, global_load_lds staging.
// MODE 0: fused QKV epilogue — RoPE; Q scaled by QSCALE (exp2-domain flash);
//         V scattered to Vt [B,KH,64,S] with the per-64-tile key PERMUTATION
//         pos = 4*(k&15) + (k>>4) so flash P-writes pack to 8B.
// MODE 1: plain fp32 C output.
// ---------------------------------------------------------------------------
template<int MODE>
__global__ __launch_bounds__(256) void gemm_abt(
    const short* __restrict__ A, const short* __restrict__ Bt,
    int M, int N, int K,
    float* __restrict__ Cf,
    short* __restrict__ Qb, short* __restrict__ Kb, short* __restrict__ Vt,
    const float* __restrict__ cosp, const float* __restrict__ sinp)
{
    const int t    = threadIdx.x;
    const int lane = t & 63;
    const int w    = t >> 6;
    const int l15  = lane & 15;
    const int l4   = lane >> 4;
    const int n0   = blockIdx.x * 128;
    const int m0   = blockIdx.y * 128;
    const int wm   = (w & 1) * 64;
    const int wn   = (w >> 1) * 64;

    __shared__ __align__(16) short As[128 * 32];
    __shared__ __align__(16) short Bs[128 * 32];

    f32x4 acc[4][4];
#pragma unroll
    for (int i = 0; i < 4; ++i)
#pragma unroll
        for (int j = 0; j < 4; ++j) acc[i][j] = (f32x4){0.f, 0.f, 0.f, 0.f};

    for (int kt = 0; kt < K; kt += 32) {
        __syncthreads();
#pragma unroll
        for (int i = 0; i < 2; ++i) {
            const int chunk = i * 256 + t;
            const int r = chunk >> 2;
            const int c = (chunk & 3) * 8;
            ldg_lds16(A  + (size_t)(m0 + r) * K + kt + c, &As[chunk * 8]);
            ldg_lds16(Bt + (size_t)(n0 + r) * K + kt + c, &Bs[chunk * 8]);
        }
        __syncthreads();

        short8 af[4], bf[4];
#pragma unroll
        for (int i = 0; i < 4; ++i)
            af[i] = *(const short8*)&As[(wm + i * 16 + l15) * 32 + l4 * 8];
#pragma unroll
        for (int j = 0; j < 4; ++j)
            bf[j] = *(const short8*)&Bs[(wn + j * 16 + l15) * 32 + l4 * 8];
#pragma unroll
        for (int i = 0; i < 4; ++i)
#pragma unroll
            for (int j = 0; j < 4; ++j)
                acc[i][j] = __builtin_amdgcn_mfma_f32_16x16x32_bf16(af[i], bf[j], acc[i][j], 0, 0, 0);
    }

    if (MODE == 1) {
#pragma unroll
        for (int i = 0; i < 4; ++i)
#pragma unroll
            for (int j = 0; j < 4; ++j)
#pragma unroll
                for (int r = 0; r < 4; ++r) {
                    const int m = m0 + wm + i * 16 + l4 * 4 + r;
                    const int n = n0 + wn + j * 16 + l15;
                    Cf[(size_t)m * N + n] = acc[i][j][r];
                }
        return;
    }

    // MODE 0: fused QKV epilogue. This wave's 64-col span = exactly one head.
    const int colbase = n0 + wn;
    if (colbase < 1024) {
        const int h = colbase >> 6;              // Q head (exp2-domain scale)
#pragma unroll
        for (int i = 0; i < 4; ++i)
#pragma unroll
            for (int r = 0; r < 4; ++r) {
                const int m = m0 + wm + i * 16 + l4 * 4 + r;
                const int b = m >> 11, s = m & (SLEN - 1);
                short* dst = Qb + (((size_t)(b * SLEN + s) * NH + h) << 6);
#pragma unroll
                for (int j = 0; j < 2; ++j) {
                    const int d = j * 16 + l15;
                    const float cv = cosp[s * HD + d];
                    const float sv = sinp[s * HD + d];
                    const float a0 = acc[i][j][r];
                    const float a1 = acc[i][j + 2][r];
                    dst[d]      = f2bf((a0 * cv - a1 * sv) * QSCALE);
                    dst[d + 32] = f2bf((a1 * cv + a0 * sv) * QSCALE);
                }
            }
    } else if (colbase < 1280) {
        const int kh = (colbase - 1024) >> 6;    // K head
#pragma unroll
        for (int i = 0; i < 4; ++i)
#pragma unroll
            for (int r = 0; r < 4; ++r) {
                const int m = m0 + wm + i * 16 + l4 * 4 + r;
                const int b = m >> 11, s = m & (SLEN - 1);
                short* dst = Kb + (((size_t)(b * SLEN + s) * NKH + kh) << 6);
#pragma unroll
                for (int j = 0; j < 2; ++j) {
                    const int d = j * 16 + l15;
                    const float cv = cosp[s * HD + d];
                    const float sv = sinp[s * HD + d];
                    const float a0 = acc[i][j][r];
                    const float a1 = acc[i][j + 2][r];
                    dst[d]      = f2bf(a0 * cv - a1 * sv);
                    dst[d + 32] = f2bf(a1 * cv + a0 * sv);
                }
            }
    } else {
        const int kh = (colbase - 1280) >> 6;    // V head -> transposed+permuted
#pragma unroll
        for (int i = 0; i < 4; ++i)
#pragma unroll
            for (int r = 0; r < 4; ++r) {
                const int m = m0 + wm + i * 16 + l4 * 4 + r;
                const int b = m >> 11, s = m & (SLEN - 1);
                // key permutation within the 64-tile: pos = 4*(k&15) + (k>>4)
                const int sp = (s & ~63) | ((s & 15) << 2) | ((s & 63) >> 4);
#pragma unroll
                for (int j = 0; j < 4; ++j) {
                    const int d = j * 16 + l15;
                    Vt[((size_t)((b * NKH + kh) * HD + d)) * SLEN + sp] = f2bf(acc[i][j][r]);
                }
            }
    }
}

// ---------------------------------------------------------------------------
// Flash attention v3 (fixed staging). Block = (b, kh, 32-query strip); 4 waves
// = the 4 Q heads of the GQA group (shared K/V tiles, identical causal
// extent). No safe-max (scores bounded; exp2 domain, Q pre-scaled). Row sums
// l via ones-column MFMA. P writes packed to b64 via the key permutation
// baked into Vt. Q frags in registers.
// ---------------------------------------------------------------------------
#define KVSTR 72   // LDS row stride (shorts) for K/V/P tiles

__global__ __launch_bounds__(256, 4) void flash_mfma(
    const short* __restrict__ Qb,   // [B,S,NH,64] bf16 (scaled QSCALE)
    const short* __restrict__ Kb,   // [B,S,NKH,64] bf16
    const short* __restrict__ Vt,   // [B,NKH,64,S] bf16, key-permuted per 64
    short* __restrict__ O)          // [B,S,NH,64] bf16
{
    const int qs   = gridDim.x - 1 - blockIdx.x;  // heavy strips first
    const int kh   = blockIdx.y;
    const int b    = blockIdx.z;
    const int t    = threadIdx.x;
    const int lane = t & 63;
    const int w    = t >> 6;
    const int h    = kh * 4 + w;                  // this wave's Q head
    const int l15  = lane & 15;
    const int l4   = lane >> 4;
    const int q0   = qs * 32;

    __shared__ __align__(16) short Ks[64 * KVSTR];
    __shared__ __align__(16) short Vs[64 * KVSTR];
    __shared__ __align__(16) short Ps[4][32 * KVSTR];

    // Q fragments in registers: rows q0 + i*16 + l15, k-chunks ks*32 + l4*8
    short8 aq[2][2];
#pragma unroll
    for (int i = 0; i < 2; ++i)
#pragma unroll
        for (int ks = 0; ks < 2; ++ks)
            aq[i][ks] = *(const short8*)(
                Qb + ((size_t)((b * SLEN + q0 + i * 16 + l15) * NH + h)) * HD + ks * 32 + l4 * 8);

    f32x4 acc[2][4];   // O accumulator [i][d-tile]
    f32x4 accl[2];     // row-sum accumulator (ones-column)
#pragma unroll
    for (int i = 0; i < 2; ++i) {
#pragma unroll
        for (int nt = 0; nt < 4; ++nt) acc[i][nt] = (f32x4){0.f, 0.f, 0.f, 0.f};
        accl[i] = (f32x4){0.f, 0.f, 0.f, 0.f};
    }

    const short8 ones8 = {0x3f80, 0x3f80, 0x3f80, 0x3f80, 0x3f80, 0x3f80, 0x3f80, 0x3f80};

    const int iters = (q0 >> 6) + 1;
    for (int kt = 0; kt < iters; ++kt) {
        const int k0 = kt * 64;
        __syncthreads();   // previous iteration's K/V frag reads done
        // Full-tile staging: 2 x 256 chunks x 16B = 8KB per tile (64 rows x
        // 64 bf16). [R4 bug: single pass only covered cols 0..31 -> NaN.]
#pragma unroll
        for (int i = 0; i < 2; ++i) {
            const int chunk = i * 256 + t;
            const int r = chunk >> 3;            // 0..63
            const int c = (chunk & 7) * 8;       // 0..56
            *(int4*)&Ks[r * KVSTR + c] =
                *(const int4*)(Kb + ((size_t)((b * SLEN + k0 + r) * NKH + kh)) * HD + c);
            *(int4*)&Vs[r * KVSTR + c] =
                *(const int4*)(Vt + ((size_t)((b * NKH + kh) * HD + r)) * SLEN + k0 + c);
        }
        __syncthreads();

        // ---- QK^T: 16 MFMA ----
        f32x4 sf[2][4];
#pragma unroll
        for (int i = 0; i < 2; ++i)
#pragma unroll
            for (int f = 0; f < 4; ++f) sf[i][f] = (f32x4){0.f, 0.f, 0.f, 0.f};
#pragma unroll
        for (int ks = 0; ks < 2; ++ks)
#pragma unroll
            for (int f = 0; f < 4; ++f) {
                const short8 bk = *(const short8*)&Ks[(f * 16 + l15) * KVSTR + ks * 32 + l4 * 8];
#pragma unroll
                for (int i = 0; i < 2; ++i)
                    sf[i][f] = __builtin_amdgcn_mfma_f32_16x16x32_bf16(aq[i][ks], bk, sf[i][f], 0, 0, 0);
            }

        // causal mask (only possible on the last tile)
        if (kt == iters - 1) {
#pragma unroll
            for (int i = 0; i < 2; ++i)
#pragma unroll
                for (int f = 0; f < 4; ++f)
#pragma unroll
                    for (int r = 0; r < 4; ++r)
                        if (k0 + f * 16 + l15 > q0 + i * 16 + l4 * 4 + r)
                            sf[i][f][r] = -1e30f;
        }

        // ---- p = exp2(s); pack 4 per lane -> one b64 write (permuted keys) ----
#pragma unroll
        for (int i = 0; i < 2; ++i)
#pragma unroll
            for (int r = 0; r < 4; ++r) {
                __align__(8) short pk[4];
#pragma unroll
                for (int f = 0; f < 4; ++f) pk[f] = f2bf(exp2f(sf[i][f][r]));
                *(int2*)&Ps[w][(i * 16 + l4 * 4 + r) * KVSTR + 4 * l15] = *(const int2*)pk;
            }

        // ---- PV: 16 MFMA + 2 ones-MFMA (Ps wave-private: no barrier) ----
#pragma unroll
        for (int ks = 0; ks < 2; ++ks) {
            short8 ap[2];
#pragma unroll
            for (int i = 0; i < 2; ++i)
                ap[i] = *(const short8*)&Ps[w][(i * 16 + l15) * KVSTR + ks * 32 + l4 * 8];
#pragma unroll
            for (int nt = 0; nt < 4; ++nt) {
                const short8 bv = *(const short8*)&Vs[(nt * 16 + l15) * KVSTR + ks * 32 + l4 * 8];
#pragma unroll
                for (int i = 0; i < 2; ++i)
                    acc[i][nt] = __builtin_amdgcn_mfma_f32_16x16x32_bf16(ap[i], bv, acc[i][nt], 0, 0, 0);
            }
#pragma unroll
            for (int i = 0; i < 2; ++i)
                accl[i] = __builtin_amdgcn_mfma_f32_16x16x32_bf16(ap[i], ones8, accl[i], 0, 0, 0);
        }
    }

    // epilogue: O = acc / l  (accl identical across l15 lanes)
#pragma unroll
    for (int i = 0; i < 2; ++i) {
        float rl[4];
#pragma unroll
        for (int r = 0; r < 4; ++r) rl[r] = 1.f / accl[i][r];
#pragma unroll
        for (int nt = 0; nt < 4; ++nt)
#pragma unroll
            for (int r = 0; r < 4; ++r) {
                const int q = q0 + i * 16 + l4 * 4 + r;
                O[((size_t)((b * SLEN + q) * NH + h)) * HD + nt * 16 + l15] =
                    f2bf(acc[i][nt][r] * rl[r]);
            }
    }
}

// ---------------------------------------------------------------------------
extern "C" void kernel_launch(void* const* d_in, const int* in_sizes, int n_in,
                              void* d_out, int out_size, void* d_ws, size_t ws_size,
                              hipStream_t stream) {
    const float* x    = (const float*)d_in[0];
    const float* cosp = (const float*)d_in[1];
    const float* sinp = (const float*)d_in[2];
    const float* wq   = (const float*)d_in[3];
    const float* wk   = (const float*)d_in[4];
    const float* wv   = (const float*)d_in[5];
    const float* wo   = (const float*)d_in[6];
    float* out = (float*)d_out;

    const int Mrows = BATCH * SLEN;   // 4096

    // workspace (bf16 elements): xb/Ob alias (xb dead before Ob written)
    short* xb = (short*)d_ws;                         // 4096*1024
    short* Ob = xb;                                   // alias
    short* wT = xb + (size_t)Mrows * 1024;            // 2560*1024
    short* Qb = wT + (size_t)2560 * 1024;             // 4096*1024
    short* Kb = Qb + (size_t)Mrows * 1024;            // 4096*256
    short* Vt = Kb + (size_t)Mrows * 256;             // 4096*256

    // x -> bf16
    cvt_bf16<<<(Mrows * DM / 8 + 255) / 256, 256, 0, stream>>>(x, xb, Mrows * DM / 8);

    // all weight transposes, one launch
    wtrans_all<<<dim3(16, 40), 256, 0, stream>>>(wq, wk, wv, wo, wT);

    // fused QKV projection + RoPE + layout scatter (N=1536)
    gemm_abt<0><<<dim3(1536 / 128, Mrows / 128), 256, 0, stream>>>(
        xb, wT, Mrows, 1536, DM, nullptr, Qb, Kb, Vt, cosp, sinp);

    // causal GQA flash attention (32-query strips, GQA-grouped waves)
    flash_mfma<<<dim3(SLEN / 32, NKH, BATCH), 256, 0, stream>>>(Qb, Kb, Vt, Ob);

    // output projection (fp32 out)
    gemm_abt<1><<<dim3(DM / 128, Mrows / 128), 256, 0, stream>>>(
        Ob, wT + (size_t)1536 * 1024, Mrows, DM, DM, out,
        nullptr, nullptr, nullptr, nullptr, nullptr);
}

// Round 6
// 204.241 us; speedup vs baseline: 8.5828x; 1.1252x over previous
//
#include <hip/hip_runtime.h>
#include <hip/hip_bf16.h>

// Problem constants
#define BATCH 2
#define SLEN  2048
#define DM    1024
#define NH    16
#define NKH   4
#define HD    64
#define NCH   4          // flash K-split: 4 chunks of 512 keys
#define PSTRIDE (BATCH * SLEN * NH * HD)   // 4,194,304 floats per chunk
#define LSTRIDE (BATCH * SLEN * NH)        // 65,536 floats per chunk

typedef __attribute__((ext_vector_type(8))) short short8;   // 8 bf16 (MFMA A/B frag)
typedef __attribute__((ext_vector_type(4))) float f32x4;    // MFMA C/D frag

// fp32 -> bf16 (RNE) as raw bits
static __device__ __forceinline__ short f2bf(float x) {
    unsigned u = __float_as_uint(x);
    u += 0x7fffu + ((u >> 16) & 1u);
    return (short)(u >> 16);
}

// async global->LDS, 16 bytes per lane. LDS dest must be uniform base + lane*16.
static __device__ __forceinline__ void ldg_lds16(const short* g, short* l) {
    __builtin_amdgcn_global_load_lds(
        (const __attribute__((address_space(1))) unsigned int*)(const void*)g,
        (__attribute__((address_space(3))) unsigned int*)(void*)l,
        16, 0, 0);
}

// log2(e)/8 : folds the 1/sqrt(HD) score scale and exp->exp2 into Q proj.
#define QSCALE 0.1803368801f

// ---------------------------------------------------------------------------
// x fp32 -> bf16 (8 elems/thread)
// ---------------------------------------------------------------------------
__global__ void cvt_bf16(const float* __restrict__ X, short* __restrict__ Xb, int total8)
{
    const int i = blockIdx.x * blockDim.x + threadIdx.x;
    if (i >= total8) return;
    const float4 v0 = ((const float4*)X)[i * 2];
    const float4 v1 = ((const float4*)X)[i * 2 + 1];
    __align__(16) short o[8];
    o[0] = f2bf(v0.x); o[1] = f2bf(v0.y); o[2] = f2bf(v0.z); o[3] = f2bf(v0.w);
    o[4] = f2bf(v1.x); o[5] = f2bf(v1.y); o[6] = f2bf(v1.z); o[7] = f2bf(v1.w);
    ((int4*)Xb)[i] = *(const int4*)o;
}

// ---------------------------------------------------------------------------
// All four weight transposes in one launch. W fp32 [1024(K)][Nc] -> T bf16
// rows (rowoff+n)[1024]. grid (16 k-tiles, 40 n-tiles).
// ---------------------------------------------------------------------------
__global__ __launch_bounds__(256) void wtrans_all(
    const float* __restrict__ wq, const float* __restrict__ wk,
    const float* __restrict__ wv, const float* __restrict__ wo,
    short* __restrict__ T)
{
    const int by = blockIdx.y;
    const float* W; int Nc, rowoff, ntile;
    if (by < 16)      { W = wq; Nc = 1024; rowoff = 0;    ntile = by; }
    else if (by < 20) { W = wk; Nc = 256;  rowoff = 1024; ntile = by - 16; }
    else if (by < 24) { W = wv; Nc = 256;  rowoff = 1280; ntile = by - 20; }
    else              { W = wo; Nc = 1024; rowoff = 1536; ntile = by - 24; }
    const int kt = blockIdx.x * 64;
    const int nt = ntile * 64;
    const int t  = threadIdx.x;
    __shared__ float tile[64][65];

#pragma unroll
    for (int i = 0; i < 4; ++i) {
        const int r = (t >> 4) + i * 16;
        const int c = (t & 15) * 4;
        const float4 v = *(const float4*)(W + (size_t)(kt + r) * Nc + nt + c);
        tile[r][c + 0] = v.x; tile[r][c + 1] = v.y;
        tile[r][c + 2] = v.z; tile[r][c + 3] = v.w;
    }
    __syncthreads();
#pragma unroll
    for (int i = 0; i < 2; ++i) {
        const int rr = (t >> 3) + i * 32;
        const int cc = (t & 7) * 8;
        __align__(16) short o[8];
#pragma unroll
        for (int j = 0; j < 8; ++j) o[j] = f2bf(tile[cc + j][rr]);
        *(int4*)(T + (size_t)(rowoff + nt + rr) * 1024 + kt + cc) = *(const int4*)o;
    }
}

// ---------------------------------------------------------------------------
// bf16 MFMA GEMM: C[M,N] = A[M,K] * Bt[N,K]^T.  128x128 tile, BK=32,
// 256 threads, global_load_lds staging.
// MODE 0: fused QKV epilogue — RoPE; Q scaled by QSCALE; V written in
//         NATURAL layout Vb [B,S,KH,64] (the transpose+permute is a separate
//         coalesced kernel — the old in-epilogue 2B scatter was the tail).
// MODE 1: plain fp32 C output.
// ---------------------------------------------------------------------------
template<int MODE>
__global__ __launch_bounds__(256) void gemm_abt(
    const short* __restrict__ A, const short* __restrict__ Bt,
    int M, int N, int K,
    float* __restrict__ Cf,
    short* __restrict__ Qb, short* __restrict__ Kb, short* __restrict__ Vb,
    const float* __restrict__ cosp, const float* __restrict__ sinp)
{
    const int t    = threadIdx.x;
    const int lane = t & 63;
    const int w    = t >> 6;
    const int l15  = lane & 15;
    const int l4   = lane >> 4;
    const int n0   = blockIdx.x * 128;
    const int m0   = blockIdx.y * 128;
    const int wm   = (w & 1) * 64;
    const int wn   = (w >> 1) * 64;

    __shared__ __align__(16) short As[128 * 32];
    __shared__ __align__(16) short Bs[128 * 32];

    f32x4 acc[4][4];
#pragma unroll
    for (int i = 0; i < 4; ++i)
#pragma unroll
        for (int j = 0; j < 4; ++j) acc[i][j] = (f32x4){0.f, 0.f, 0.f, 0.f};

    for (int kt = 0; kt < K; kt += 32) {
        __syncthreads();
#pragma unroll
        for (int i = 0; i < 2; ++i) {
            const int chunk = i * 256 + t;
            const int r = chunk >> 2;
            const int c = (chunk & 3) * 8;
            ldg_lds16(A  + (size_t)(m0 + r) * K + kt + c, &As[chunk * 8]);
            ldg_lds16(Bt + (size_t)(n0 + r) * K + kt + c, &Bs[chunk * 8]);
        }
        __syncthreads();

        short8 af[4], bf[4];
#pragma unroll
        for (int i = 0; i < 4; ++i)
            af[i] = *(const short8*)&As[(wm + i * 16 + l15) * 32 + l4 * 8];
#pragma unroll
        for (int j = 0; j < 4; ++j)
            bf[j] = *(const short8*)&Bs[(wn + j * 16 + l15) * 32 + l4 * 8];
#pragma unroll
        for (int i = 0; i < 4; ++i)
#pragma unroll
            for (int j = 0; j < 4; ++j)
                acc[i][j] = __builtin_amdgcn_mfma_f32_16x16x32_bf16(af[i], bf[j], acc[i][j], 0, 0, 0);
    }

    if (MODE == 1) {
#pragma unroll
        for (int i = 0; i < 4; ++i)
#pragma unroll
            for (int j = 0; j < 4; ++j)
#pragma unroll
                for (int r = 0; r < 4; ++r) {
                    const int m = m0 + wm + i * 16 + l4 * 4 + r;
                    const int n = n0 + wn + j * 16 + l15;
                    Cf[(size_t)m * N + n] = acc[i][j][r];
                }
        return;
    }

    // MODE 0: fused QKV epilogue. This wave's 64-col span = exactly one head.
    const int colbase = n0 + wn;
    if (colbase < 1024) {
        const int h = colbase >> 6;              // Q head (exp2-domain scale)
#pragma unroll
        for (int i = 0; i < 4; ++i)
#pragma unroll
            for (int r = 0; r < 4; ++r) {
                const int m = m0 + wm + i * 16 + l4 * 4 + r;
                const int b = m >> 11, s = m & (SLEN - 1);
                short* dst = Qb + (((size_t)(b * SLEN + s) * NH + h) << 6);
#pragma unroll
                for (int j = 0; j < 2; ++j) {
                    const int d = j * 16 + l15;
                    const float cv = cosp[s * HD + d];
                    const float sv = sinp[s * HD + d];
                    const float a0 = acc[i][j][r];
                    const float a1 = acc[i][j + 2][r];
                    dst[d]      = f2bf((a0 * cv - a1 * sv) * QSCALE);
                    dst[d + 32] = f2bf((a1 * cv + a0 * sv) * QSCALE);
                }
            }
    } else if (colbase < 1280) {
        const int kh = (colbase - 1024) >> 6;    // K head
#pragma unroll
        for (int i = 0; i < 4; ++i)
#pragma unroll
            for (int r = 0; r < 4; ++r) {
                const int m = m0 + wm + i * 16 + l4 * 4 + r;
                const int b = m >> 11, s = m & (SLEN - 1);
                short* dst = Kb + (((size_t)(b * SLEN + s) * NKH + kh) << 6);
#pragma unroll
                for (int j = 0; j < 2; ++j) {
                    const int d = j * 16 + l15;
                    const float cv = cosp[s * HD + d];
                    const float sv = sinp[s * HD + d];
                    const float a0 = acc[i][j][r];
                    const float a1 = acc[i][j + 2][r];
                    dst[d]      = f2bf(a0 * cv - a1 * sv);
                    dst[d + 32] = f2bf(a1 * cv + a0 * sv);
                }
            }
    } else {
        const int kh = (colbase - 1280) >> 6;    // V head -> natural layout
#pragma unroll
        for (int i = 0; i < 4; ++i)
#pragma unroll
            for (int r = 0; r < 4; ++r) {
                const int m = m0 + wm + i * 16 + l4 * 4 + r;
                const int b = m >> 11, s = m & (SLEN - 1);
                short* dst = Vb + (((size_t)(b * SLEN + s) * NKH + kh) << 6);
#pragma unroll
                for (int j = 0; j < 4; ++j)
                    dst[j * 16 + l15] = f2bf(acc[i][j][r]);
            }
    }
}

// ---------------------------------------------------------------------------
// V transpose: Vb bf16 [B,S,KH,64] -> Vt bf16 [B,KH,64(d),S], with the
// per-64-tile key permutation sp = 4*(u&15) + (u>>4) baked in (so flash
// P-writes pack to b64). Coalesced on both sides via LDS tile.
// ---------------------------------------------------------------------------
__global__ __launch_bounds__(256) void vtrans_b(
    const short* __restrict__ Vb, short* __restrict__ Vt)
{
    const int s0 = blockIdx.x * 64;
    const int kh = blockIdx.y;
    const int b  = blockIdx.z;
    const int t  = threadIdx.x;
    __shared__ short tile[64][72];

#pragma unroll
    for (int i = 0; i < 2; ++i) {
        const int chunk = i * 256 + t;
        const int r = chunk >> 3;            // s row 0..63
        const int c = (chunk & 7) * 8;       // d col
        *(int4*)&tile[r][c] =
            *(const int4*)(Vb + (((size_t)(b * SLEN + s0 + r) * NKH + kh) << 6) + c);
    }
    __syncthreads();
#pragma unroll
    for (int i = 0; i < 2; ++i) {
        const int chunk = i * 256 + t;
        const int d  = chunk >> 3;           // 0..63
        const int sc = (chunk & 7) * 8;      // sp chunk base
        __align__(16) short o[8];
#pragma unroll
        for (int j = 0; j < 8; ++j) {
            const int sp = sc + j;
            const int u  = ((sp & 3) << 4) | (sp >> 2);   // inverse permutation
            o[j] = tile[u][d];
        }
        *(int4*)(Vt + ((size_t)((b * NKH + kh) * HD + d)) * SLEN + s0 + sc) = *(const int4*)o;
    }
}

// ---------------------------------------------------------------------------
// Flash attention v4: K-split. Block = (b, kh, 32-query strip, key-chunk of
// 512). 4 waves = 4 Q heads of the GQA group. exp2-domain, no running max, so
// partial (acc, l) across chunks combine by plain addition. Strips with a
// single active chunk (q0 < 512) write final output directly.
// ---------------------------------------------------------------------------
#define KVSTR 72   // LDS row stride (shorts) for K/V/P tiles

__global__ __launch_bounds__(256, 4) void flash_mfma(
    const short* __restrict__ Qb,   // [B,S,NH,64] bf16 (scaled QSCALE)
    const short* __restrict__ Kb,   // [B,S,NKH,64] bf16
    const short* __restrict__ Vt,   // [B,NKH,64,S] bf16, key-permuted per 64
    short* __restrict__ O,          // [B,S,NH,64] bf16 (direct path, s<512)
    float* __restrict__ Op,         // [NCH][B,S,NH,64] fp32 partial O
    float* __restrict__ Lp)         // [NCH][B,S,NH]    fp32 partial l
{
    const int qs = 63 - blockIdx.x;               // heavy strips first
    const int kc = blockIdx.y & 3;
    if (kc * 16 > qs) return;                     // inactive (chunk > diagonal)
    const int kh = blockIdx.y >> 2;
    const int b  = blockIdx.z;
    const int t    = threadIdx.x;
    const int lane = t & 63;
    const int w    = t >> 6;
    const int h    = kh * 4 + w;                  // this wave's Q head
    const int l15  = lane & 15;
    const int l4   = lane >> 4;
    const int q0   = qs * 32;

    __shared__ __align__(16) short Ks[64 * KVSTR];
    __shared__ __align__(16) short Vs[64 * KVSTR];
    __shared__ __align__(16) short Ps[4][32 * KVSTR];

    // Q fragments in registers
    short8 aq[2][2];
#pragma unroll
    for (int i = 0; i < 2; ++i)
#pragma unroll
        for (int ks = 0; ks < 2; ++ks)
            aq[i][ks] = *(const short8*)(
                Qb + ((size_t)((b * SLEN + q0 + i * 16 + l15) * NH + h)) * HD + ks * 32 + l4 * 8);

    f32x4 acc[2][4];
    f32x4 accl[2];
#pragma unroll
    for (int i = 0; i < 2; ++i) {
#pragma unroll
        for (int nt = 0; nt < 4; ++nt) acc[i][nt] = (f32x4){0.f, 0.f, 0.f, 0.f};
        accl[i] = (f32x4){0.f, 0.f, 0.f, 0.f};
    }

    const short8 ones8 = {0x3f80, 0x3f80, 0x3f80, 0x3f80, 0x3f80, 0x3f80, 0x3f80, 0x3f80};

    const int ntiles = (q0 >> 6) + 1;             // global causal tile count
    const int kt0  = kc * 8;
    const int kend = (kt0 + 8 < ntiles) ? kt0 + 8 : ntiles;

    for (int kt = kt0; kt < kend; ++kt) {
        const int k0 = kt * 64;
        __syncthreads();
#pragma unroll
        for (int i = 0; i < 2; ++i) {
            const int chunk = i * 256 + t;
            const int r = chunk >> 3;
            const int c = (chunk & 7) * 8;
            *(int4*)&Ks[r * KVSTR + c] =
                *(const int4*)(Kb + ((size_t)((b * SLEN + k0 + r) * NKH + kh)) * HD + c);
            *(int4*)&Vs[r * KVSTR + c] =
                *(const int4*)(Vt + ((size_t)((b * NKH + kh) * HD + r)) * SLEN + k0 + c);
        }
        __syncthreads();

        // ---- QK^T: 16 MFMA ----
        f32x4 sf[2][4];
#pragma unroll
        for (int i = 0; i < 2; ++i)
#pragma unroll
            for (int f = 0; f < 4; ++f) sf[i][f] = (f32x4){0.f, 0.f, 0.f, 0.f};
#pragma unroll
        for (int ks = 0; ks < 2; ++ks)
#pragma unroll
            for (int f = 0; f < 4; ++f) {
                const short8 bk = *(const short8*)&Ks[(f * 16 + l15) * KVSTR + ks * 32 + l4 * 8];
#pragma unroll
                for (int i = 0; i < 2; ++i)
                    sf[i][f] = __builtin_amdgcn_mfma_f32_16x16x32_bf16(aq[i][ks], bk, sf[i][f], 0, 0, 0);
            }

        // causal mask (only the globally-last tile can violate)
        if (kt == ntiles - 1) {
#pragma unroll
            for (int i = 0; i < 2; ++i)
#pragma unroll
                for (int f = 0; f < 4; ++f)
#pragma unroll
                    for (int r = 0; r < 4; ++r)
                        if (k0 + f * 16 + l15 > q0 + i * 16 + l4 * 4 + r)
                            sf[i][f][r] = -1e30f;
        }

        // ---- p = exp2(s); pack 4 per lane -> one b64 write (permuted keys) ----
#pragma unroll
        for (int i = 0; i < 2; ++i)
#pragma unroll
            for (int r = 0; r < 4; ++r) {
                __align__(8) short pk[4];
#pragma unroll
                for (int f = 0; f < 4; ++f) pk[f] = f2bf(exp2f(sf[i][f][r]));
                *(int2*)&Ps[w][(i * 16 + l4 * 4 + r) * KVSTR + 4 * l15] = *(const int2*)pk;
            }

        // ---- PV: 16 MFMA + 2 ones-MFMA (Ps wave-private: no barrier) ----
#pragma unroll
        for (int ks = 0; ks < 2; ++ks) {
            short8 ap[2];
#pragma unroll
            for (int i = 0; i < 2; ++i)
                ap[i] = *(const short8*)&Ps[w][(i * 16 + l15) * KVSTR + ks * 32 + l4 * 8];
#pragma unroll
            for (int nt = 0; nt < 4; ++nt) {
                const short8 bv = *(const short8*)&Vs[(nt * 16 + l15) * KVSTR + ks * 32 + l4 * 8];
#pragma unroll
                for (int i = 0; i < 2; ++i)
                    acc[i][nt] = __builtin_amdgcn_mfma_f32_16x16x32_bf16(ap[i], bv, acc[i][nt], 0, 0, 0);
            }
#pragma unroll
            for (int i = 0; i < 2; ++i)
                accl[i] = __builtin_amdgcn_mfma_f32_16x16x32_bf16(ap[i], ones8, accl[i], 0, 0, 0);
        }
    }

    if (q0 < 512) {
        // single active chunk: normalized direct write
#pragma unroll
        for (int i = 0; i < 2; ++i) {
            float rl[4];
#pragma unroll
            for (int r = 0; r < 4; ++r) rl[r] = 1.f / accl[i][r];
#pragma unroll
            for (int nt = 0; nt < 4; ++nt)
#pragma unroll
                for (int r = 0; r < 4; ++r) {
                    const int q = q0 + i * 16 + l4 * 4 + r;
                    O[((size_t)((b * SLEN + q) * NH + h)) * HD + nt * 16 + l15] =
                        f2bf(acc[i][nt][r] * rl[r]);
                }
        }
    } else {
        // partial write (combined by addition in combine_k)
        const size_t pbase = (size_t)kc * PSTRIDE;
#pragma unroll
        for (int i = 0; i < 2; ++i)
#pragma unroll
            for (int nt = 0; nt < 4; ++nt)
#pragma unroll
                for (int r = 0; r < 4; ++r) {
                    const int q = q0 + i * 16 + l4 * 4 + r;
                    Op[pbase + ((size_t)((b * SLEN + q) * NH + h)) * HD + nt * 16 + l15] =
                        acc[i][nt][r];
                }
        if (l15 == 0) {
#pragma unroll
            for (int i = 0; i < 2; ++i)
#pragma unroll
                for (int r = 0; r < 4; ++r) {
                    const int q = q0 + i * 16 + l4 * 4 + r;
                    Lp[(size_t)kc * LSTRIDE + (size_t)(b * SLEN + q) * NH + h] = accl[i][r];
                }
        }
    }
}

// ---------------------------------------------------------------------------
// Combine K-split partials for s >= 512: O = (Σ acc_kc) / (Σ l_kc), bf16 out.
// One thread per (b, s, h, 4-d group). Fully coalesced float4 reads.
// ---------------------------------------------------------------------------
__global__ void combine_k(const float* __restrict__ Op, const float* __restrict__ Lp,
                          short* __restrict__ O)
{
    const int idx = blockIdx.x * 256 + threadIdx.x;   // < B*1536*NH*16
    const int dq = idx & 15;
    const int h  = (idx >> 4) & 15;
    const int rr = idx >> 8;                          // 0..3071
    const int b  = rr / 1536;
    const int s  = 512 + (rr - b * 1536);
    const int nact = (s >> 9) + 1;                    // 2..4 active chunks
    const size_t row = (size_t)(b * SLEN + s) * NH + h;

    float4 o = {0.f, 0.f, 0.f, 0.f};
    float l = 0.f;
    for (int kc = 0; kc < nact; ++kc) {
        const float4 p = *(const float4*)(Op + (size_t)kc * PSTRIDE + row * HD + dq * 4);
        o.x += p.x; o.y += p.y; o.z += p.z; o.w += p.w;
        l += Lp[(size_t)kc * LSTRIDE + row];
    }
    const float rl = 1.f / l;
    __align__(8) short pk[4];
    pk[0] = f2bf(o.x * rl); pk[1] = f2bf(o.y * rl);
    pk[2] = f2bf(o.z * rl); pk[3] = f2bf(o.w * rl);
    *(int2*)(O + row * HD + dq * 4) = *(const int2*)pk;
}

// ---------------------------------------------------------------------------
extern "C" void kernel_launch(void* const* d_in, const int* in_sizes, int n_in,
                              void* d_out, int out_size, void* d_ws, size_t ws_size,
                              hipStream_t stream) {
    const float* x    = (const float*)d_in[0];
    const float* cosp = (const float*)d_in[1];
    const float* sinp = (const float*)d_in[2];
    const float* wq   = (const float*)d_in[3];
    const float* wk   = (const float*)d_in[4];
    const float* wv   = (const float*)d_in[5];
    const float* wo   = (const float*)d_in[6];
    float* out = (float*)d_out;

    const int Mrows = BATCH * SLEN;   // 4096

    // workspace layout (bf16 elems then fp32): xb/Ob alias (xb dead by then)
    short* xb = (short*)d_ws;                         // 4096*1024 bf16 (8 MB)
    short* Ob = xb;                                   // alias
    short* wT = xb + (size_t)Mrows * 1024;            // 2560*1024 bf16 (5 MB)
    short* Qb = wT + (size_t)2560 * 1024;             // 4096*1024 bf16 (8 MB)
    short* Kb = Qb + (size_t)Mrows * 1024;            // 4096*256  bf16 (2 MB)
    short* Vt = Kb + (size_t)Mrows * 256;             // 4096*256  bf16 (2 MB)
    short* Vb = Vt + (size_t)Mrows * 256;             // 4096*256  bf16 (2 MB)
    float* Op = (float*)(Vb + (size_t)Mrows * 256);   // NCH*4.19M fp32 (67 MB)
    float* Lp = Op + (size_t)NCH * PSTRIDE;           // NCH*65536 fp32 (1 MB)

    // x -> bf16
    cvt_bf16<<<(Mrows * DM / 8 + 255) / 256, 256, 0, stream>>>(x, xb, Mrows * DM / 8);

    // all weight transposes, one launch
    wtrans_all<<<dim3(16, 40), 256, 0, stream>>>(wq, wk, wv, wo, wT);

    // fused QKV projection + RoPE (V in natural layout)
    gemm_abt<0><<<dim3(1536 / 128, Mrows / 128), 256, 0, stream>>>(
        xb, wT, Mrows, 1536, DM, nullptr, Qb, Kb, Vb, cosp, sinp);

    // V transpose + key permutation (coalesced)
    vtrans_b<<<dim3(SLEN / 64, NKH, BATCH), 256, 0, stream>>>(Vb, Vt);

    // causal GQA flash attention, K-split into NCH chunks of 512 keys
    flash_mfma<<<dim3(SLEN / 32, NKH * NCH, BATCH), 256, 0, stream>>>(
        Qb, Kb, Vt, Ob, Op, Lp);

    // combine partials for s >= 512
    combine_k<<<(BATCH * 1536 * NH * 16) / 256, 256, 0, stream>>>(Op, Lp, Ob);

    // output projection (fp32 out)
    gemm_abt<1><<<dim3(DM / 128, Mrows / 128), 256, 0, stream>>>(
        Ob, wT + (size_t)1536 * 1024, Mrows, DM, DM, out,
        nullptr, nullptr, nullptr, nullptr, nullptr);
}

// Round 7
// 191.193 us; speedup vs baseline: 9.1686x; 1.0683x over previous
//
#include <hip/hip_runtime.h>
#include <hip/hip_bf16.h>

// Problem constants
#define BATCH 2
#define SLEN  2048
#define DM    1024
#define NH    16
#define NKH   4
#define HD    64
#define NCH   4          // flash K-split: 4 chunks of 512 keys
#define PSTRIDE (BATCH * SLEN * NH * HD)   // 4,194,304 floats per chunk
#define LSTRIDE (BATCH * SLEN * NH)        // 65,536 floats per chunk

typedef __attribute__((ext_vector_type(8))) short short8;   // 8 bf16 (MFMA A/B frag)
typedef __attribute__((ext_vector_type(4))) float f32x4;    // MFMA C/D frag

// fp32 -> bf16 (RNE) as raw bits
static __device__ __forceinline__ short f2bf(float x) {
    unsigned u = __float_as_uint(x);
    u += 0x7fffu + ((u >> 16) & 1u);
    return (short)(u >> 16);
}

// async global->LDS, 16 bytes per lane. LDS dest must be uniform base + lane*16.
static __device__ __forceinline__ void ldg_lds16(const short* g, short* l) {
    __builtin_amdgcn_global_load_lds(
        (const __attribute__((address_space(1))) unsigned int*)(const void*)g,
        (__attribute__((address_space(3))) unsigned int*)(void*)l,
        16, 0, 0);
}

// log2(e)/8 : folds the 1/sqrt(HD) score scale and exp->exp2 into Q proj.
#define QSCALE 0.1803368801f

// ---------------------------------------------------------------------------
// x fp32 -> bf16 (8 elems/thread)
// ---------------------------------------------------------------------------
__global__ void cvt_bf16(const float* __restrict__ X, short* __restrict__ Xb, int total8)
{
    const int i = blockIdx.x * blockDim.x + threadIdx.x;
    if (i >= total8) return;
    const float4 v0 = ((const float4*)X)[i * 2];
    const float4 v1 = ((const float4*)X)[i * 2 + 1];
    __align__(16) short o[8];
    o[0] = f2bf(v0.x); o[1] = f2bf(v0.y); o[2] = f2bf(v0.z); o[3] = f2bf(v0.w);
    o[4] = f2bf(v1.x); o[5] = f2bf(v1.y); o[6] = f2bf(v1.z); o[7] = f2bf(v1.w);
    ((int4*)Xb)[i] = *(const int4*)o;
}

// ---------------------------------------------------------------------------
// All four weight transposes in one launch. W fp32 [1024(K)][Nc] -> T bf16
// rows (rowoff+n)[1024]. grid (16 k-tiles, 40 n-tiles).
// ---------------------------------------------------------------------------
__global__ __launch_bounds__(256) void wtrans_all(
    const float* __restrict__ wq, const float* __restrict__ wk,
    const float* __restrict__ wv, const float* __restrict__ wo,
    short* __restrict__ T)
{
    const int by = blockIdx.y;
    const float* W; int Nc, rowoff, ntile;
    if (by < 16)      { W = wq; Nc = 1024; rowoff = 0;    ntile = by; }
    else if (by < 20) { W = wk; Nc = 256;  rowoff = 1024; ntile = by - 16; }
    else if (by < 24) { W = wv; Nc = 256;  rowoff = 1280; ntile = by - 20; }
    else              { W = wo; Nc = 1024; rowoff = 1536; ntile = by - 24; }
    const int kt = blockIdx.x * 64;
    const int nt = ntile * 64;
    const int t  = threadIdx.x;
    __shared__ float tile[64][65];

#pragma unroll
    for (int i = 0; i < 4; ++i) {
        const int r = (t >> 4) + i * 16;
        const int c = (t & 15) * 4;
        const float4 v = *(const float4*)(W + (size_t)(kt + r) * Nc + nt + c);
        tile[r][c + 0] = v.x; tile[r][c + 1] = v.y;
        tile[r][c + 2] = v.z; tile[r][c + 3] = v.w;
    }
    __syncthreads();
#pragma unroll
    for (int i = 0; i < 2; ++i) {
        const int rr = (t >> 3) + i * 32;
        const int cc = (t & 7) * 8;
        __align__(16) short o[8];
#pragma unroll
        for (int j = 0; j < 8; ++j) o[j] = f2bf(tile[cc + j][rr]);
        *(int4*)(T + (size_t)(rowoff + nt + rr) * 1024 + kt + cc) = *(const int4*)o;
    }
}

// ---------------------------------------------------------------------------
// bf16 MFMA GEMM: C[M,N] = A[M,K] * Bt[N,K]^T.  64x128 tile (M x N), BK=64,
// 256 threads (4 waves in 2x2, wave tile 32x64), global_load_lds staging.
// Retile rationale: 128x128 gave only 384/256 blocks = 1-1.5 blocks/CU; the
// barrier vmcnt-drain was naked. 64x128 doubles block count (3/2 per CU).
// MODE 0: fused QKV epilogue (RoPE, QSCALE, V natural layout).
// MODE 1: plain fp32 C output.
// ---------------------------------------------------------------------------
template<int MODE>
__global__ __launch_bounds__(256) void gemm_abt(
    const short* __restrict__ A, const short* __restrict__ Bt,
    int M, int N, int K,
    float* __restrict__ Cf,
    short* __restrict__ Qb, short* __restrict__ Kb, short* __restrict__ Vb,
    const float* __restrict__ cosp, const float* __restrict__ sinp)
{
    const int t    = threadIdx.x;
    const int lane = t & 63;
    const int w    = t >> 6;
    const int l15  = lane & 15;
    const int l4   = lane >> 4;
    const int n0   = blockIdx.x * 128;
    const int m0   = blockIdx.y * 64;
    const int wm   = (w & 1) * 32;
    const int wn   = (w >> 1) * 64;

    __shared__ __align__(16) short As[64 * 64];    // 8 KB
    __shared__ __align__(16) short Bs[128 * 64];   // 16 KB

    f32x4 acc[2][4];
#pragma unroll
    for (int i = 0; i < 2; ++i)
#pragma unroll
        for (int j = 0; j < 4; ++j) acc[i][j] = (f32x4){0.f, 0.f, 0.f, 0.f};

    for (int kt = 0; kt < K; kt += 64) {
        __syncthreads();
#pragma unroll
        for (int i = 0; i < 2; ++i) {              // A: 512 chunks
            const int chunk = i * 256 + t;
            const int r = chunk >> 3;
            const int c = (chunk & 7) * 8;
            ldg_lds16(A + (size_t)(m0 + r) * K + kt + c, &As[chunk * 8]);
        }
#pragma unroll
        for (int i = 0; i < 4; ++i) {              // B: 1024 chunks
            const int chunk = i * 256 + t;
            const int r = chunk >> 3;
            const int c = (chunk & 7) * 8;
            ldg_lds16(Bt + (size_t)(n0 + r) * K + kt + c, &Bs[chunk * 8]);
        }
        __syncthreads();

#pragma unroll
        for (int k2 = 0; k2 < 2; ++k2) {
            short8 af[2], bf[4];
#pragma unroll
            for (int i = 0; i < 2; ++i)
                af[i] = *(const short8*)&As[(wm + i * 16 + l15) * 64 + k2 * 32 + l4 * 8];
#pragma unroll
            for (int j = 0; j < 4; ++j)
                bf[j] = *(const short8*)&Bs[(wn + j * 16 + l15) * 64 + k2 * 32 + l4 * 8];
#pragma unroll
            for (int i = 0; i < 2; ++i)
#pragma unroll
                for (int j = 0; j < 4; ++j)
                    acc[i][j] = __builtin_amdgcn_mfma_f32_16x16x32_bf16(af[i], bf[j], acc[i][j], 0, 0, 0);
        }
    }

    if (MODE == 1) {
#pragma unroll
        for (int i = 0; i < 2; ++i)
#pragma unroll
            for (int j = 0; j < 4; ++j)
#pragma unroll
                for (int r = 0; r < 4; ++r) {
                    const int m = m0 + wm + i * 16 + l4 * 4 + r;
                    const int n = n0 + wn + j * 16 + l15;
                    Cf[(size_t)m * N + n] = acc[i][j][r];
                }
        return;
    }

    // MODE 0: fused QKV epilogue. This wave's 64-col span = exactly one head.
    const int colbase = n0 + wn;
    if (colbase < 1024) {
        const int h = colbase >> 6;              // Q head (exp2-domain scale)
#pragma unroll
        for (int i = 0; i < 2; ++i)
#pragma unroll
            for (int r = 0; r < 4; ++r) {
                const int m = m0 + wm + i * 16 + l4 * 4 + r;
                const int b = m >> 11, s = m & (SLEN - 1);
                short* dst = Qb + (((size_t)(b * SLEN + s) * NH + h) << 6);
#pragma unroll
                for (int j = 0; j < 2; ++j) {
                    const int d = j * 16 + l15;
                    const float cv = cosp[s * HD + d];
                    const float sv = sinp[s * HD + d];
                    const float a0 = acc[i][j][r];
                    const float a1 = acc[i][j + 2][r];
                    dst[d]      = f2bf((a0 * cv - a1 * sv) * QSCALE);
                    dst[d + 32] = f2bf((a1 * cv + a0 * sv) * QSCALE);
                }
            }
    } else if (colbase < 1280) {
        const int kh = (colbase - 1024) >> 6;    // K head
#pragma unroll
        for (int i = 0; i < 2; ++i)
#pragma unroll
            for (int r = 0; r < 4; ++r) {
                const int m = m0 + wm + i * 16 + l4 * 4 + r;
                const int b = m >> 11, s = m & (SLEN - 1);
                short* dst = Kb + (((size_t)(b * SLEN + s) * NKH + kh) << 6);
#pragma unroll
                for (int j = 0; j < 2; ++j) {
                    const int d = j * 16 + l15;
                    const float cv = cosp[s * HD + d];
                    const float sv = sinp[s * HD + d];
                    const float a0 = acc[i][j][r];
                    const float a1 = acc[i][j + 2][r];
                    dst[d]      = f2bf(a0 * cv - a1 * sv);
                    dst[d + 32] = f2bf(a1 * cv + a0 * sv);
                }
            }
    } else {
        const int kh = (colbase - 1280) >> 6;    // V head -> natural layout
#pragma unroll
        for (int i = 0; i < 2; ++i)
#pragma unroll
            for (int r = 0; r < 4; ++r) {
                const int m = m0 + wm + i * 16 + l4 * 4 + r;
                const int b = m >> 11, s = m & (SLEN - 1);
                short* dst = Vb + (((size_t)(b * SLEN + s) * NKH + kh) << 6);
#pragma unroll
                for (int j = 0; j < 4; ++j)
                    dst[j * 16 + l15] = f2bf(acc[i][j][r]);
            }
    }
}

// ---------------------------------------------------------------------------
// V transpose: Vb bf16 [B,S,KH,64] -> Vt bf16 [B,KH,64(d),S], with the
// per-64-tile key permutation sp = 4*(u&15) + (u>>4) baked in (so flash
// P-writes pack to b64). Coalesced on both sides via LDS tile.
// ---------------------------------------------------------------------------
__global__ __launch_bounds__(256) void vtrans_b(
    const short* __restrict__ Vb, short* __restrict__ Vt)
{
    const int s0 = blockIdx.x * 64;
    const int kh = blockIdx.y;
    const int b  = blockIdx.z;
    const int t  = threadIdx.x;
    __shared__ short tile[64][72];

#pragma unroll
    for (int i = 0; i < 2; ++i) {
        const int chunk = i * 256 + t;
        const int r = chunk >> 3;            // s row 0..63
        const int c = (chunk & 7) * 8;       // d col
        *(int4*)&tile[r][c] =
            *(const int4*)(Vb + (((size_t)(b * SLEN + s0 + r) * NKH + kh) << 6) + c);
    }
    __syncthreads();
#pragma unroll
    for (int i = 0; i < 2; ++i) {
        const int chunk = i * 256 + t;
        const int d  = chunk >> 3;           // 0..63
        const int sc = (chunk & 7) * 8;      // sp chunk base
        __align__(16) short o[8];
#pragma unroll
        for (int j = 0; j < 8; ++j) {
            const int sp = sc + j;
            const int u  = ((sp & 3) << 4) | (sp >> 2);   // inverse permutation
            o[j] = tile[u][d];
        }
        *(int4*)(Vt + ((size_t)((b * NKH + kh) * HD + d)) * SLEN + s0 + sc) = *(const int4*)o;
    }
}

// ---------------------------------------------------------------------------
// Flash attention v5: K-split + global_load_lds staging with XOR swizzle.
// Ks/Vs are LINEAR 64x64 tiles (global_load_lds needs lane-linear dest);
// logical (row, col8) lives at physical col8^(row&7), applied to the SOURCE
// address at staging and to the frag-read index. Frag reads: 16 l15-rows x
// 8 phys offsets -> 2 rows/offset = 2-way = free.
// ---------------------------------------------------------------------------
#define PSTR 72    // Ps row stride (shorts), padded

__global__ __launch_bounds__(256, 4) void flash_mfma(
    const short* __restrict__ Qb,   // [B,S,NH,64] bf16 (scaled QSCALE)
    const short* __restrict__ Kb,   // [B,S,NKH,64] bf16
    const short* __restrict__ Vt,   // [B,NKH,64,S] bf16, key-permuted per 64
    short* __restrict__ O,          // [B,S,NH,64] bf16 (direct path, s<512)
    float* __restrict__ Op,         // [NCH][B,S,NH,64] fp32 partial O
    float* __restrict__ Lp)         // [NCH][B,S,NH]    fp32 partial l
{
    const int qs = 63 - blockIdx.x;               // heavy strips first
    const int kc = blockIdx.y & 3;
    if (kc * 16 > qs) return;                     // inactive (chunk > diagonal)
    const int kh = blockIdx.y >> 2;
    const int b  = blockIdx.z;
    const int t    = threadIdx.x;
    const int lane = t & 63;
    const int w    = t >> 6;
    const int h    = kh * 4 + w;                  // this wave's Q head
    const int l15  = lane & 15;
    const int l4   = lane >> 4;
    const int q0   = qs * 32;
    const int sw   = l15 & 7;                     // frag-read swizzle key

    __shared__ __align__(16) short Ks[64 * 64];   // 8 KB, linear+swizzled
    __shared__ __align__(16) short Vs[64 * 64];   // 8 KB, linear+swizzled
    __shared__ __align__(16) short Ps[4][32 * PSTR];

    // Q fragments in registers
    short8 aq[2][2];
#pragma unroll
    for (int i = 0; i < 2; ++i)
#pragma unroll
        for (int ks = 0; ks < 2; ++ks)
            aq[i][ks] = *(const short8*)(
                Qb + ((size_t)((b * SLEN + q0 + i * 16 + l15) * NH + h)) * HD + ks * 32 + l4 * 8);

    f32x4 acc[2][4];
    f32x4 accl[2];
#pragma unroll
    for (int i = 0; i < 2; ++i) {
#pragma unroll
        for (int nt = 0; nt < 4; ++nt) acc[i][nt] = (f32x4){0.f, 0.f, 0.f, 0.f};
        accl[i] = (f32x4){0.f, 0.f, 0.f, 0.f};
    }

    const short8 ones8 = {0x3f80, 0x3f80, 0x3f80, 0x3f80, 0x3f80, 0x3f80, 0x3f80, 0x3f80};

    const int ntiles = (q0 >> 6) + 1;             // global causal tile count
    const int kt0  = kc * 8;
    const int kend = (kt0 + 8 < ntiles) ? kt0 + 8 : ntiles;

    for (int kt = kt0; kt < kend; ++kt) {
        const int k0 = kt * 64;
        __syncthreads();
        // staging via global_load_lds; source col swizzled so that logical
        // (row, col8) sits at physical col8^(row&7)
#pragma unroll
        for (int i = 0; i < 2; ++i) {
            const int chunk = i * 256 + t;
            const int r  = chunk >> 3;            // 0..63
            const int c8 = chunk & 7;
            const int cs = (c8 ^ (r & 7)) * 8;    // source column (shorts)
            ldg_lds16(Kb + ((size_t)((b * SLEN + k0 + r) * NKH + kh)) * HD + cs,
                      &Ks[chunk * 8]);
            ldg_lds16(Vt + ((size_t)((b * NKH + kh) * HD + r)) * SLEN + k0 + cs,
                      &Vs[chunk * 8]);
        }
        __syncthreads();

        // ---- QK^T: 16 MFMA ----
        f32x4 sf[2][4];
#pragma unroll
        for (int i = 0; i < 2; ++i)
#pragma unroll
            for (int f = 0; f < 4; ++f) sf[i][f] = (f32x4){0.f, 0.f, 0.f, 0.f};
#pragma unroll
        for (int ks = 0; ks < 2; ++ks)
#pragma unroll
            for (int f = 0; f < 4; ++f) {
                const short8 bk = *(const short8*)
                    &Ks[(f * 16 + l15) * 64 + ((ks * 4 + l4) ^ sw) * 8];
#pragma unroll
                for (int i = 0; i < 2; ++i)
                    sf[i][f] = __builtin_amdgcn_mfma_f32_16x16x32_bf16(aq[i][ks], bk, sf[i][f], 0, 0, 0);
            }

        // causal mask (only the globally-last tile can violate)
        if (kt == ntiles - 1) {
#pragma unroll
            for (int i = 0; i < 2; ++i)
#pragma unroll
                for (int f = 0; f < 4; ++f)
#pragma unroll
                    for (int r = 0; r < 4; ++r)
                        if (k0 + f * 16 + l15 > q0 + i * 16 + l4 * 4 + r)
                            sf[i][f][r] = -1e30f;
        }

        // ---- p = exp2(s); pack 4 per lane -> one b64 write (permuted keys) ----
#pragma unroll
        for (int i = 0; i < 2; ++i)
#pragma unroll
            for (int r = 0; r < 4; ++r) {
                __align__(8) short pk[4];
#pragma unroll
                for (int f = 0; f < 4; ++f) pk[f] = f2bf(exp2f(sf[i][f][r]));
                *(int2*)&Ps[w][(i * 16 + l4 * 4 + r) * PSTR + 4 * l15] = *(const int2*)pk;
            }

        // ---- PV: 16 MFMA + 2 ones-MFMA (Ps wave-private: no barrier) ----
#pragma unroll
        for (int ks = 0; ks < 2; ++ks) {
            short8 ap[2];
#pragma unroll
            for (int i = 0; i < 2; ++i)
                ap[i] = *(const short8*)&Ps[w][(i * 16 + l15) * PSTR + ks * 32 + l4 * 8];
#pragma unroll
            for (int nt = 0; nt < 4; ++nt) {
                const short8 bv = *(const short8*)
                    &Vs[(nt * 16 + l15) * 64 + ((ks * 4 + l4) ^ sw) * 8];
#pragma unroll
                for (int i = 0; i < 2; ++i)
                    acc[i][nt] = __builtin_amdgcn_mfma_f32_16x16x32_bf16(ap[i], bv, acc[i][nt], 0, 0, 0);
            }
#pragma unroll
            for (int i = 0; i < 2; ++i)
                accl[i] = __builtin_amdgcn_mfma_f32_16x16x32_bf16(ap[i], ones8, accl[i], 0, 0, 0);
        }
    }

    if (q0 < 512) {
        // single active chunk: normalized direct write
#pragma unroll
        for (int i = 0; i < 2; ++i) {
            float rl[4];
#pragma unroll
            for (int r = 0; r < 4; ++r) rl[r] = 1.f / accl[i][r];
#pragma unroll
            for (int nt = 0; nt < 4; ++nt)
#pragma unroll
                for (int r = 0; r < 4; ++r) {
                    const int q = q0 + i * 16 + l4 * 4 + r;
                    O[((size_t)((b * SLEN + q) * NH + h)) * HD + nt * 16 + l15] =
                        f2bf(acc[i][nt][r] * rl[r]);
                }
        }
    } else {
        // partial write (combined by addition in combine_k)
        const size_t pbase = (size_t)kc * PSTRIDE;
#pragma unroll
        for (int i = 0; i < 2; ++i)
#pragma unroll
            for (int nt = 0; nt < 4; ++nt)
#pragma unroll
                for (int r = 0; r < 4; ++r) {
                    const int q = q0 + i * 16 + l4 * 4 + r;
                    Op[pbase + ((size_t)((b * SLEN + q) * NH + h)) * HD + nt * 16 + l15] =
                        acc[i][nt][r];
                }
        if (l15 == 0) {
#pragma unroll
            for (int i = 0; i < 2; ++i)
#pragma unroll
                for (int r = 0; r < 4; ++r) {
                    const int q = q0 + i * 16 + l4 * 4 + r;
                    Lp[(size_t)kc * LSTRIDE + (size_t)(b * SLEN + q) * NH + h] = accl[i][r];
                }
        }
    }
}

// ---------------------------------------------------------------------------
// Combine K-split partials for s >= 512: O = (Σ acc_kc) / (Σ l_kc), bf16 out.
// ---------------------------------------------------------------------------
__global__ void combine_k(const float* __restrict__ Op, const float* __restrict__ Lp,
                          short* __restrict__ O)
{
    const int idx = blockIdx.x * 256 + threadIdx.x;   // < B*1536*NH*16
    const int dq = idx & 15;
    const int h  = (idx >> 4) & 15;
    const int rr = idx >> 8;                          // 0..3071
    const int b  = rr / 1536;
    const int s  = 512 + (rr - b * 1536);
    const int nact = (s >> 9) + 1;                    // 2..4 active chunks
    const size_t row = (size_t)(b * SLEN + s) * NH + h;

    float4 o = {0.f, 0.f, 0.f, 0.f};
    float l = 0.f;
    for (int kc = 0; kc < nact; ++kc) {
        const float4 p = *(const float4*)(Op + (size_t)kc * PSTRIDE + row * HD + dq * 4);
        o.x += p.x; o.y += p.y; o.z += p.z; o.w += p.w;
        l += Lp[(size_t)kc * LSTRIDE + row];
    }
    const float rl = 1.f / l;
    __align__(8) short pk[4];
    pk[0] = f2bf(o.x * rl); pk[1] = f2bf(o.y * rl);
    pk[2] = f2bf(o.z * rl); pk[3] = f2bf(o.w * rl);
    *(int2*)(O + row * HD + dq * 4) = *(const int2*)pk;
}

// ---------------------------------------------------------------------------
extern "C" void kernel_launch(void* const* d_in, const int* in_sizes, int n_in,
                              void* d_out, int out_size, void* d_ws, size_t ws_size,
                              hipStream_t stream) {
    const float* x    = (const float*)d_in[0];
    const float* cosp = (const float*)d_in[1];
    const float* sinp = (const float*)d_in[2];
    const float* wq   = (const float*)d_in[3];
    const float* wk   = (const float*)d_in[4];
    const float* wv   = (const float*)d_in[5];
    const float* wo   = (const float*)d_in[6];
    float* out = (float*)d_out;

    const int Mrows = BATCH * SLEN;   // 4096

    // workspace layout (bf16 elems then fp32): xb/Ob alias (xb dead by then)
    short* xb = (short*)d_ws;                         // 4096*1024 bf16 (8 MB)
    short* Ob = xb;                                   // alias
    short* wT = xb + (size_t)Mrows * 1024;            // 2560*1024 bf16 (5 MB)
    short* Qb = wT + (size_t)2560 * 1024;             // 4096*1024 bf16 (8 MB)
    short* Kb = Qb + (size_t)Mrows * 1024;            // 4096*256  bf16 (2 MB)
    short* Vt = Kb + (size_t)Mrows * 256;             // 4096*256  bf16 (2 MB)
    short* Vb = Vt + (size_t)Mrows * 256;             // 4096*256  bf16 (2 MB)
    float* Op = (float*)(Vb + (size_t)Mrows * 256);   // NCH*4.19M fp32 (67 MB)
    float* Lp = Op + (size_t)NCH * PSTRIDE;           // NCH*65536 fp32 (1 MB)

    // x -> bf16
    cvt_bf16<<<(Mrows * DM / 8 + 255) / 256, 256, 0, stream>>>(x, xb, Mrows * DM / 8);

    // all weight transposes, one launch
    wtrans_all<<<dim3(16, 40), 256, 0, stream>>>(wq, wk, wv, wo, wT);

    // fused QKV projection + RoPE (V in natural layout). grid 12x64 = 768
    gemm_abt<0><<<dim3(1536 / 128, Mrows / 64), 256, 0, stream>>>(
        xb, wT, Mrows, 1536, DM, nullptr, Qb, Kb, Vb, cosp, sinp);

    // V transpose + key permutation (coalesced)
    vtrans_b<<<dim3(SLEN / 64, NKH, BATCH), 256, 0, stream>>>(Vb, Vt);

    // causal GQA flash attention, K-split into NCH chunks of 512 keys
    flash_mfma<<<dim3(SLEN / 32, NKH * NCH, BATCH), 256, 0, stream>>>(
        Qb, Kb, Vt, Ob, Op, Lp);

    // combine partials for s >= 512
    combine_k<<<(BATCH * 1536 * NH * 16) / 256, 256, 0, stream>>>(Op, Lp, Ob);

    // output projection (fp32 out). grid 8x64 = 512
    gemm_abt<1><<<dim3(DM / 128, Mrows / 64), 256, 0, stream>>>(
        Ob, wT + (size_t)1536 * 1024, Mrows, DM, DM, out,
        nullptr, nullptr, nullptr, nullptr, nullptr);
}

// Round 8
// 187.502 us; speedup vs baseline: 9.3490x; 1.0197x over previous
//
#include <hip/hip_runtime.h>
#include <hip/hip_bf16.h>

// Problem constants
#define BATCH 2
#define SLEN  2048
#define DM    1024
#define NH    16
#define NKH   4
#define HD    64
#define NCH   4          // flash K-split: 4 chunks of 512 keys
#define PSTRIDE (BATCH * SLEN * NH * HD)   // 4,194,304 floats per chunk
#define LSTRIDE (BATCH * SLEN * NH)        // 65,536 floats per chunk

typedef __attribute__((ext_vector_type(8))) short short8;   // 8 bf16 (MFMA A/B frag)
typedef __attribute__((ext_vector_type(4))) float f32x4;    // MFMA C/D frag

// fp32 -> bf16 (RNE) as raw bits
static __device__ __forceinline__ short f2bf(float x) {
    unsigned u = __float_as_uint(x);
    u += 0x7fffu + ((u >> 16) & 1u);
    return (short)(u >> 16);
}

// async global->LDS, 16 bytes per lane. LDS dest must be uniform base + lane*16.
static __device__ __forceinline__ void ldg_lds16(const short* g, short* l) {
    __builtin_amdgcn_global_load_lds(
        (const __attribute__((address_space(1))) unsigned int*)(const void*)g,
        (__attribute__((address_space(3))) unsigned int*)(void*)l,
        16, 0, 0);
}

// log2(e)/8 : folds the 1/sqrt(HD) score scale and exp->exp2 into Q proj.
#define QSCALE 0.1803368801f

// ---------------------------------------------------------------------------
// Fused preprocessing: weight transposes (by < 40) + x fp32->bf16 (by >= 40).
// W fp32 [1024(K)][Nc] -> T bf16 rows (rowoff+n)[1024].
// ---------------------------------------------------------------------------
__global__ __launch_bounds__(256) void prep_all(
    const float* __restrict__ wq, const float* __restrict__ wk,
    const float* __restrict__ wv, const float* __restrict__ wo,
    short* __restrict__ T,
    const float* __restrict__ X, short* __restrict__ Xb)
{
    const int by = blockIdx.y;
    const int t  = threadIdx.x;

    if (by >= 40) {
        // x -> bf16: 128 blocks x 256 threads x 16 float8 groups
        const int blk = (by - 40) * 16 + blockIdx.x;    // 0..127
#pragma unroll
        for (int j = 0; j < 16; ++j) {
            const int i = blk * 4096 + j * 256 + t;
            const float4 v0 = ((const float4*)X)[i * 2];
            const float4 v1 = ((const float4*)X)[i * 2 + 1];
            __align__(16) short o[8];
            o[0] = f2bf(v0.x); o[1] = f2bf(v0.y); o[2] = f2bf(v0.z); o[3] = f2bf(v0.w);
            o[4] = f2bf(v1.x); o[5] = f2bf(v1.y); o[6] = f2bf(v1.z); o[7] = f2bf(v1.w);
            ((int4*)Xb)[i] = *(const int4*)o;
        }
        return;
    }

    const float* W; int Nc, rowoff, ntile;
    if (by < 16)      { W = wq; Nc = 1024; rowoff = 0;    ntile = by; }
    else if (by < 20) { W = wk; Nc = 256;  rowoff = 1024; ntile = by - 16; }
    else if (by < 24) { W = wv; Nc = 256;  rowoff = 1280; ntile = by - 20; }
    else              { W = wo; Nc = 1024; rowoff = 1536; ntile = by - 24; }
    const int kt = blockIdx.x * 64;
    const int nt = ntile * 64;
    __shared__ float tile[64][65];

#pragma unroll
    for (int i = 0; i < 4; ++i) {
        const int r = (t >> 4) + i * 16;
        const int c = (t & 15) * 4;
        const float4 v = *(const float4*)(W + (size_t)(kt + r) * Nc + nt + c);
        tile[r][c + 0] = v.x; tile[r][c + 1] = v.y;
        tile[r][c + 2] = v.z; tile[r][c + 3] = v.w;
    }
    __syncthreads();
#pragma unroll
    for (int i = 0; i < 2; ++i) {
        const int rr = (t >> 3) + i * 32;
        const int cc = (t & 7) * 8;
        __align__(16) short o[8];
#pragma unroll
        for (int j = 0; j < 8; ++j) o[j] = f2bf(tile[cc + j][rr]);
        *(int4*)(T + (size_t)(rowoff + nt + rr) * 1024 + kt + cc) = *(const int4*)o;
    }
}

// ---------------------------------------------------------------------------
// bf16 MFMA GEMM: C[M,N] = A[M,K] * Bt[N,K]^T.  64x128 tile (M x N), BK=64,
// 256 threads (4 waves in 2x2, wave tile 32x64), global_load_lds staging.
// MODE 0: fused QKV epilogue (RoPE, QSCALE, V natural layout).
// MODE 1: plain fp32 C output.
// ---------------------------------------------------------------------------
template<int MODE>
__global__ __launch_bounds__(256) void gemm_abt(
    const short* __restrict__ A, const short* __restrict__ Bt,
    int M, int N, int K,
    float* __restrict__ Cf,
    short* __restrict__ Qb, short* __restrict__ Kb, short* __restrict__ Vb,
    const float* __restrict__ cosp, const float* __restrict__ sinp)
{
    const int t    = threadIdx.x;
    const int lane = t & 63;
    const int w    = t >> 6;
    const int l15  = lane & 15;
    const int l4   = lane >> 4;
    const int n0   = blockIdx.x * 128;
    const int m0   = blockIdx.y * 64;
    const int wm   = (w & 1) * 32;
    const int wn   = (w >> 1) * 64;

    __shared__ __align__(16) short As[64 * 64];    // 8 KB
    __shared__ __align__(16) short Bs[128 * 64];   // 16 KB

    f32x4 acc[2][4];
#pragma unroll
    for (int i = 0; i < 2; ++i)
#pragma unroll
        for (int j = 0; j < 4; ++j) acc[i][j] = (f32x4){0.f, 0.f, 0.f, 0.f};

    for (int kt = 0; kt < K; kt += 64) {
        __syncthreads();
#pragma unroll
        for (int i = 0; i < 2; ++i) {              // A: 512 chunks
            const int chunk = i * 256 + t;
            const int r = chunk >> 3;
            const int c = (chunk & 7) * 8;
            ldg_lds16(A + (size_t)(m0 + r) * K + kt + c, &As[chunk * 8]);
        }
#pragma unroll
        for (int i = 0; i < 4; ++i) {              // B: 1024 chunks
            const int chunk = i * 256 + t;
            const int r = chunk >> 3;
            const int c = (chunk & 7) * 8;
            ldg_lds16(Bt + (size_t)(n0 + r) * K + kt + c, &Bs[chunk * 8]);
        }
        __syncthreads();

#pragma unroll
        for (int k2 = 0; k2 < 2; ++k2) {
            short8 af[2], bf[4];
#pragma unroll
            for (int i = 0; i < 2; ++i)
                af[i] = *(const short8*)&As[(wm + i * 16 + l15) * 64 + k2 * 32 + l4 * 8];
#pragma unroll
            for (int j = 0; j < 4; ++j)
                bf[j] = *(const short8*)&Bs[(wn + j * 16 + l15) * 64 + k2 * 32 + l4 * 8];
#pragma unroll
            for (int i = 0; i < 2; ++i)
#pragma unroll
                for (int j = 0; j < 4; ++j)
                    acc[i][j] = __builtin_amdgcn_mfma_f32_16x16x32_bf16(af[i], bf[j], acc[i][j], 0, 0, 0);
        }
    }

    if (MODE == 1) {
#pragma unroll
        for (int i = 0; i < 2; ++i)
#pragma unroll
            for (int j = 0; j < 4; ++j)
#pragma unroll
                for (int r = 0; r < 4; ++r) {
                    const int m = m0 + wm + i * 16 + l4 * 4 + r;
                    const int n = n0 + wn + j * 16 + l15;
                    Cf[(size_t)m * N + n] = acc[i][j][r];
                }
        return;
    }

    // MODE 0: fused QKV epilogue. This wave's 64-col span = exactly one head.
    const int colbase = n0 + wn;
    if (colbase < 1024) {
        const int h = colbase >> 6;              // Q head (exp2-domain scale)
#pragma unroll
        for (int i = 0; i < 2; ++i)
#pragma unroll
            for (int r = 0; r < 4; ++r) {
                const int m = m0 + wm + i * 16 + l4 * 4 + r;
                const int b = m >> 11, s = m & (SLEN - 1);
                short* dst = Qb + (((size_t)(b * SLEN + s) * NH + h) << 6);
#pragma unroll
                for (int j = 0; j < 2; ++j) {
                    const int d = j * 16 + l15;
                    const float cv = cosp[s * HD + d];
                    const float sv = sinp[s * HD + d];
                    const float a0 = acc[i][j][r];
                    const float a1 = acc[i][j + 2][r];
                    dst[d]      = f2bf((a0 * cv - a1 * sv) * QSCALE);
                    dst[d + 32] = f2bf((a1 * cv + a0 * sv) * QSCALE);
                }
            }
    } else if (colbase < 1280) {
        const int kh = (colbase - 1024) >> 6;    // K head
#pragma unroll
        for (int i = 0; i < 2; ++i)
#pragma unroll
            for (int r = 0; r < 4; ++r) {
                const int m = m0 + wm + i * 16 + l4 * 4 + r;
                const int b = m >> 11, s = m & (SLEN - 1);
                short* dst = Kb + (((size_t)(b * SLEN + s) * NKH + kh) << 6);
#pragma unroll
                for (int j = 0; j < 2; ++j) {
                    const int d = j * 16 + l15;
                    const float cv = cosp[s * HD + d];
                    const float sv = sinp[s * HD + d];
                    const float a0 = acc[i][j][r];
                    const float a1 = acc[i][j + 2][r];
                    dst[d]      = f2bf(a0 * cv - a1 * sv);
                    dst[d + 32] = f2bf(a1 * cv + a0 * sv);
                }
            }
    } else {
        const int kh = (colbase - 1280) >> 6;    // V head -> natural layout
#pragma unroll
        for (int i = 0; i < 2; ++i)
#pragma unroll
            for (int r = 0; r < 4; ++r) {
                const int m = m0 + wm + i * 16 + l4 * 4 + r;
                const int b = m >> 11, s = m & (SLEN - 1);
                short* dst = Vb + (((size_t)(b * SLEN + s) * NKH + kh) << 6);
#pragma unroll
                for (int j = 0; j < 4; ++j)
                    dst[j * 16 + l15] = f2bf(acc[i][j][r]);
            }
    }
}

// ---------------------------------------------------------------------------
// V transpose: Vb bf16 [B,S,KH,64] -> Vt bf16 [B,KH,64(d),S], with the
// per-64-tile key permutation sp = 4*(u&15) + (u>>4) baked in.
// ---------------------------------------------------------------------------
__global__ __launch_bounds__(256) void vtrans_b(
    const short* __restrict__ Vb, short* __restrict__ Vt)
{
    const int s0 = blockIdx.x * 64;
    const int kh = blockIdx.y;
    const int b  = blockIdx.z;
    const int t  = threadIdx.x;
    __shared__ short tile[64][72];

#pragma unroll
    for (int i = 0; i < 2; ++i) {
        const int chunk = i * 256 + t;
        const int r = chunk >> 3;            // s row 0..63
        const int c = (chunk & 7) * 8;       // d col
        *(int4*)&tile[r][c] =
            *(const int4*)(Vb + (((size_t)(b * SLEN + s0 + r) * NKH + kh) << 6) + c);
    }
    __syncthreads();
#pragma unroll
    for (int i = 0; i < 2; ++i) {
        const int chunk = i * 256 + t;
        const int d  = chunk >> 3;           // 0..63
        const int sc = (chunk & 7) * 8;      // sp chunk base
        __align__(16) short o[8];
#pragma unroll
        for (int j = 0; j < 8; ++j) {
            const int sp = sc + j;
            const int u  = ((sp & 3) << 4) | (sp >> 2);   // inverse permutation
            o[j] = tile[u][d];
        }
        *(int4*)(Vt + ((size_t)((b * NKH + kh) * HD + d)) * SLEN + s0 + sc) = *(const int4*)o;
    }
}

// ---------------------------------------------------------------------------
// Flash attention v6: K-split + DOUBLE-BUFFERED K/V staging, ONE barrier per
// tile. Stage tile kt+1 into buf^1 right after the barrier, compute tile kt
// from buf — the vmcnt drain for the staging lands at the NEXT barrier, after
// ~500 cyc of compute (R7 was 2 barriers/iter with a naked vmcnt(0) drain =
// ~1000 cyc/iter latency-bound). XOR swizzle col8^=(row&7) as in R7.
// ---------------------------------------------------------------------------
#define PSTR 72    // Ps row stride (shorts), padded

__global__ __launch_bounds__(256, 3) void flash_mfma(
    const short* __restrict__ Qb,   // [B,S,NH,64] bf16 (scaled QSCALE)
    const short* __restrict__ Kb,   // [B,S,NKH,64] bf16
    const short* __restrict__ Vt,   // [B,NKH,64,S] bf16, key-permuted per 64
    short* __restrict__ O,          // [B,S,NH,64] bf16 (direct path, s<512)
    float* __restrict__ Op,         // [NCH][B,S,NH,64] fp32 partial O
    float* __restrict__ Lp)         // [NCH][B,S,NH]    fp32 partial l
{
    const int qs = 63 - blockIdx.x;               // heavy strips first
    const int kc = blockIdx.y & 3;
    if (kc * 16 > qs) return;                     // inactive (chunk > diagonal)
    const int kh = blockIdx.y >> 2;
    const int b  = blockIdx.z;
    const int t    = threadIdx.x;
    const int lane = t & 63;
    const int w    = t >> 6;
    const int h    = kh * 4 + w;                  // this wave's Q head
    const int l15  = lane & 15;
    const int l4   = lane >> 4;
    const int q0   = qs * 32;
    const int sw   = l15 & 7;                     // frag-read swizzle key

    __shared__ __align__(16) short Ks[2][64 * 64];   // 16 KB, dbuf
    __shared__ __align__(16) short Vs[2][64 * 64];   // 16 KB, dbuf
    __shared__ __align__(16) short Ps[4][32 * PSTR]; // 18 KB

    // staging: 512 chunks per tile, source col swizzled
    const int r_st  = t >> 3;                      // 0..31 (+32 for 2nd half)
    const int c8_st = t & 7;

    // Q fragments in registers
    short8 aq[2][2];
#pragma unroll
    for (int i = 0; i < 2; ++i)
#pragma unroll
        for (int ks = 0; ks < 2; ++ks)
            aq[i][ks] = *(const short8*)(
                Qb + ((size_t)((b * SLEN + q0 + i * 16 + l15) * NH + h)) * HD + ks * 32 + l4 * 8);

    f32x4 acc[2][4];
    f32x4 accl[2];
#pragma unroll
    for (int i = 0; i < 2; ++i) {
#pragma unroll
        for (int nt = 0; nt < 4; ++nt) acc[i][nt] = (f32x4){0.f, 0.f, 0.f, 0.f};
        accl[i] = (f32x4){0.f, 0.f, 0.f, 0.f};
    }

    const short8 ones8 = {0x3f80, 0x3f80, 0x3f80, 0x3f80, 0x3f80, 0x3f80, 0x3f80, 0x3f80};

    const int ntiles = (q0 >> 6) + 1;             // global causal tile count
    const int kt0  = kc * 8;
    const int kend = (kt0 + 8 < ntiles) ? kt0 + 8 : ntiles;

#define STAGE(BI, K0)                                                          \
    {                                                                          \
        _Pragma("unroll")                                                      \
        for (int i_ = 0; i_ < 2; ++i_) {                                       \
            const int r  = i_ * 32 + r_st;                                     \
            const int cs = (c8_st ^ (r & 7)) * 8;                              \
            const int ch = i_ * 256 + t;                                       \
            ldg_lds16(Kb + ((size_t)((b * SLEN + (K0) + r) * NKH + kh)) * HD + cs, \
                      &Ks[BI][ch * 8]);                                        \
            ldg_lds16(Vt + ((size_t)((b * NKH + kh) * HD + r)) * SLEN + (K0) + cs, \
                      &Vs[BI][ch * 8]);                                        \
        }                                                                      \
    }

    STAGE(0, kt0 * 64)

    for (int kt = kt0; kt < kend; ++kt) {
        const int bi = (kt - kt0) & 1;
        __syncthreads();   // drains own staging vmcnt; all waves past prev compute
        if (kt + 1 < kend) STAGE(bi ^ 1, (kt + 1) * 64)

        // ---- QK^T: 16 MFMA ----
        f32x4 sf[2][4];
#pragma unroll
        for (int i = 0; i < 2; ++i)
#pragma unroll
            for (int f = 0; f < 4; ++f) sf[i][f] = (f32x4){0.f, 0.f, 0.f, 0.f};
#pragma unroll
        for (int ks = 0; ks < 2; ++ks)
#pragma unroll
            for (int f = 0; f < 4; ++f) {
                const short8 bk = *(const short8*)
                    &Ks[bi][(f * 16 + l15) * 64 + ((ks * 4 + l4) ^ sw) * 8];
#pragma unroll
                for (int i = 0; i < 2; ++i)
                    sf[i][f] = __builtin_amdgcn_mfma_f32_16x16x32_bf16(aq[i][ks], bk, sf[i][f], 0, 0, 0);
            }

        // causal mask (only the globally-last tile can violate)
        if (kt == ntiles - 1) {
            const int k0 = kt * 64;
#pragma unroll
            for (int i = 0; i < 2; ++i)
#pragma unroll
                for (int f = 0; f < 4; ++f)
#pragma unroll
                    for (int r = 0; r < 4; ++r)
                        if (k0 + f * 16 + l15 > q0 + i * 16 + l4 * 4 + r)
                            sf[i][f][r] = -1e30f;
        }

        // ---- p = exp2(s); pack 4 per lane -> one b64 write (permuted keys) ----
#pragma unroll
        for (int i = 0; i < 2; ++i)
#pragma unroll
            for (int r = 0; r < 4; ++r) {
                __align__(8) short pk[4];
#pragma unroll
                for (int f = 0; f < 4; ++f) pk[f] = f2bf(exp2f(sf[i][f][r]));
                *(int2*)&Ps[w][(i * 16 + l4 * 4 + r) * PSTR + 4 * l15] = *(const int2*)pk;
            }

        // ---- PV: 16 MFMA + 2 ones-MFMA (Ps wave-private: no barrier) ----
#pragma unroll
        for (int ks = 0; ks < 2; ++ks) {
            short8 ap[2];
#pragma unroll
            for (int i = 0; i < 2; ++i)
                ap[i] = *(const short8*)&Ps[w][(i * 16 + l15) * PSTR + ks * 32 + l4 * 8];
#pragma unroll
            for (int nt = 0; nt < 4; ++nt) {
                const short8 bv = *(const short8*)
                    &Vs[bi][(nt * 16 + l15) * 64 + ((ks * 4 + l4) ^ sw) * 8];
#pragma unroll
                for (int i = 0; i < 2; ++i)
                    acc[i][nt] = __builtin_amdgcn_mfma_f32_16x16x32_bf16(ap[i], bv, acc[i][nt], 0, 0, 0);
            }
#pragma unroll
            for (int i = 0; i < 2; ++i)
                accl[i] = __builtin_amdgcn_mfma_f32_16x16x32_bf16(ap[i], ones8, accl[i], 0, 0, 0);
        }
    }

    if (q0 < 512) {
        // single active chunk: normalized direct write
#pragma unroll
        for (int i = 0; i < 2; ++i) {
            float rl[4];
#pragma unroll
            for (int r = 0; r < 4; ++r) rl[r] = 1.f / accl[i][r];
#pragma unroll
            for (int nt = 0; nt < 4; ++nt)
#pragma unroll
                for (int r = 0; r < 4; ++r) {
                    const int q = q0 + i * 16 + l4 * 4 + r;
                    O[((size_t)((b * SLEN + q) * NH + h)) * HD + nt * 16 + l15] =
                        f2bf(acc[i][nt][r] * rl[r]);
                }
        }
    } else {
        // partial write (combined by addition in combine_k)
        const size_t pbase = (size_t)kc * PSTRIDE;
#pragma unroll
        for (int i = 0; i < 2; ++i)
#pragma unroll
            for (int nt = 0; nt < 4; ++nt)
#pragma unroll
                for (int r = 0; r < 4; ++r) {
                    const int q = q0 + i * 16 + l4 * 4 + r;
                    Op[pbase + ((size_t)((b * SLEN + q) * NH + h)) * HD + nt * 16 + l15] =
                        acc[i][nt][r];
                }
        if (l15 == 0) {
#pragma unroll
            for (int i = 0; i < 2; ++i)
#pragma unroll
                for (int r = 0; r < 4; ++r) {
                    const int q = q0 + i * 16 + l4 * 4 + r;
                    Lp[(size_t)kc * LSTRIDE + (size_t)(b * SLEN + q) * NH + h] = accl[i][r];
                }
        }
    }
}

// ---------------------------------------------------------------------------
// Combine K-split partials for s >= 512: O = (Σ acc_kc) / (Σ l_kc), bf16 out.
// ---------------------------------------------------------------------------
__global__ void combine_k(const float* __restrict__ Op, const float* __restrict__ Lp,
                          short* __restrict__ O)
{
    const int idx = blockIdx.x * 256 + threadIdx.x;   // < B*1536*NH*16
    const int dq = idx & 15;
    const int h  = (idx >> 4) & 15;
    const int rr = idx >> 8;                          // 0..3071
    const int b  = rr / 1536;
    const int s  = 512 + (rr - b * 1536);
    const int nact = (s >> 9) + 1;                    // 2..4 active chunks
    const size_t row = (size_t)(b * SLEN + s) * NH + h;

    float4 o = {0.f, 0.f, 0.f, 0.f};
    float l = 0.f;
    for (int kc = 0; kc < nact; ++kc) {
        const float4 p = *(const float4*)(Op + (size_t)kc * PSTRIDE + row * HD + dq * 4);
        o.x += p.x; o.y += p.y; o.z += p.z; o.w += p.w;
        l += Lp[(size_t)kc * LSTRIDE + row];
    }
    const float rl = 1.f / l;
    __align__(8) short pk[4];
    pk[0] = f2bf(o.x * rl); pk[1] = f2bf(o.y * rl);
    pk[2] = f2bf(o.z * rl); pk[3] = f2bf(o.w * rl);
    *(int2*)(O + row * HD + dq * 4) = *(const int2*)pk;
}

// ---------------------------------------------------------------------------
extern "C" void kernel_launch(void* const* d_in, const int* in_sizes, int n_in,
                              void* d_out, int out_size, void* d_ws, size_t ws_size,
                              hipStream_t stream) {
    const float* x    = (const float*)d_in[0];
    const float* cosp = (const float*)d_in[1];
    const float* sinp = (const float*)d_in[2];
    const float* wq   = (const float*)d_in[3];
    const float* wk   = (const float*)d_in[4];
    const float* wv   = (const float*)d_in[5];
    const float* wo   = (const float*)d_in[6];
    float* out = (float*)d_out;

    const int Mrows = BATCH * SLEN;   // 4096

    // workspace layout (bf16 elems then fp32): xb/Ob alias (xb dead by then)
    short* xb = (short*)d_ws;                         // 4096*1024 bf16 (8 MB)
    short* Ob = xb;                                   // alias
    short* wT = xb + (size_t)Mrows * 1024;            // 2560*1024 bf16 (5 MB)
    short* Qb = wT + (size_t)2560 * 1024;             // 4096*1024 bf16 (8 MB)
    short* Kb = Qb + (size_t)Mrows * 1024;            // 4096*256  bf16 (2 MB)
    short* Vt = Kb + (size_t)Mrows * 256;             // 4096*256  bf16 (2 MB)
    short* Vb = Vt + (size_t)Mrows * 256;             // 4096*256  bf16 (2 MB)
    float* Op = (float*)(Vb + (size_t)Mrows * 256);   // NCH*4.19M fp32 (67 MB)
    float* Lp = Op + (size_t)NCH * PSTRIDE;           // NCH*65536 fp32 (1 MB)

    // fused: weight transposes + x->bf16
    prep_all<<<dim3(16, 48), 256, 0, stream>>>(wq, wk, wv, wo, wT, x, xb);

    // fused QKV projection + RoPE (V in natural layout). grid 12x64 = 768
    gemm_abt<0><<<dim3(1536 / 128, Mrows / 64), 256, 0, stream>>>(
        xb, wT, Mrows, 1536, DM, nullptr, Qb, Kb, Vb, cosp, sinp);

    // V transpose + key permutation (coalesced)
    vtrans_b<<<dim3(SLEN / 64, NKH, BATCH), 256, 0, stream>>>(Vb, Vt);

    // causal GQA flash attention, K-split into NCH chunks of 512 keys
    flash_mfma<<<dim3(SLEN / 32, NKH * NCH, BATCH), 256, 0, stream>>>(
        Qb, Kb, Vt, Ob, Op, Lp);

    // combine partials for s >= 512
    combine_k<<<(BATCH * 1536 * NH * 16) / 256, 256, 0, stream>>>(Op, Lp, Ob);

    // output projection (fp32 out). grid 8x64 = 512
    gemm_abt<1><<<dim3(DM / 128, Mrows / 64), 256, 0, stream>>>(
        Ob, wT + (size_t)1536 * 1024, Mrows, DM, DM, out,
        nullptr, nullptr, nullptr, nullptr, nullptr);
}